// Round 1
// baseline (3274.209 us; speedup 1.0000x reference)
//
#include <hip/hip_runtime.h>

#define N_NODES 50000
#define N_EDGES 800000
#define IN_DIM 64
#define HID_DIM 128
#define OUT_DIM 10
#define N_GRAPHS 64

// ---------------- degree / norm ----------------

__global__ void k_init(int* __restrict__ degi, float* __restrict__ psum, int* __restrict__ cnt) {
    int i = blockIdx.x * blockDim.x + threadIdx.x;
    if (i < N_NODES) degi[i] = 1;                 // self-loop contributes 1 to deg
    if (i < N_GRAPHS * HID_DIM) psum[i] = 0.f;
    if (i < N_GRAPHS) cnt[i] = 0;
}

__global__ void k_degcount(const int* __restrict__ dst, int* __restrict__ degi) {
    int e = blockIdx.x * blockDim.x + threadIdx.x;
    if (e < N_EDGES) atomicAdd(&degi[dst[e]], 1);
}

__global__ void k_dinv(const int* __restrict__ degi, float* __restrict__ dinv) {
    int i = blockIdx.x * blockDim.x + threadIdx.x;
    if (i < N_NODES) dinv[i] = rsqrtf((float)degi[i]);
}

// ---------------- GEMM: O[m][n] = sum_k X[m][k] * W[n][k], N=128 ----------------
// 64-node x 128-feat tile per 256-thread block; k-major LDS staging, KC=64 chunks.

template<int K>
__global__ __launch_bounds__(256) void k_gemm_nt(const float* __restrict__ X,
                                                 const float* __restrict__ W,
                                                 float* __restrict__ O) {
    constexpr int KC = 64;
    __shared__ float wsT[KC * 132];   // [k][n], pad 132 keeps float4 alignment, breaks bank stride
    __shared__ float xsT[KC * 68];    // [k][m]
    const int tid = threadIdx.x;
    const int bm = blockIdx.x * 64;
    const int fg = tid & 31;          // feature group: cols 4*fg..4*fg+3
    const int ng = tid >> 5;          // node group:   rows 8*ng..8*ng+7

    float acc[8][4];
#pragma unroll
    for (int i = 0; i < 8; i++)
#pragma unroll
        for (int j = 0; j < 4; j++) acc[i][j] = 0.f;

    for (int k0 = 0; k0 < K; k0 += KC) {
        for (int i = tid; i < HID_DIM * KC; i += 256) {
            int n = i >> 6, k = i & 63;
            wsT[k * 132 + n] = W[n * K + k0 + k];
        }
        for (int i = tid; i < 64 * KC; i += 256) {
            int r = i >> 6, k = i & 63;
            int m = bm + r;
            xsT[k * 68 + r] = (m < N_NODES) ? X[(size_t)m * K + k0 + k] : 0.f;
        }
        __syncthreads();
#pragma unroll 4
        for (int k = 0; k < KC; k++) {
            const float4 w4 = *(const float4*)&wsT[k * 132 + 4 * fg];
            const float4 xa = *(const float4*)&xsT[k * 68 + 8 * ng];
            const float4 xb = *(const float4*)&xsT[k * 68 + 8 * ng + 4];
            float xv[8] = {xa.x, xa.y, xa.z, xa.w, xb.x, xb.y, xb.z, xb.w};
            float wv[4] = {w4.x, w4.y, w4.z, w4.w};
#pragma unroll
            for (int i = 0; i < 8; i++)
#pragma unroll
                for (int j = 0; j < 4; j++)
                    acc[i][j] = fmaf(xv[i], wv[j], acc[i][j]);
        }
        __syncthreads();
    }
#pragma unroll
    for (int i = 0; i < 8; i++) {
        int m = bm + 8 * ng + i;
        if (m < N_NODES)
            *(float4*)&O[(size_t)m * HID_DIM + 4 * fg] =
                make_float4(acc[i][0], acc[i][1], acc[i][2], acc[i][3]);
    }
}

// ---------------- aggregation ----------------

// agg[i] = dinv[i]^2 * t[i]   (self-loop term; also zero-inits the accumulator)
__global__ void k_agg_init(const float* __restrict__ t, const float* __restrict__ dinv,
                           float* __restrict__ agg) {
    int i = blockIdx.x * blockDim.x + threadIdx.x;   // exact grid: N_NODES*32
    int m = i >> 5;
    float s = dinv[m] * dinv[m];
    float4 v = ((const float4*)t)[i];
    ((float4*)agg)[i] = make_float4(v.x * s, v.y * s, v.z * s, v.w * s);
}

// one thread per (edge, float4-chunk): agg[dst] += dinv[s]*dinv[d] * t[src]
__global__ void k_scatter(const float* __restrict__ t, const int* __restrict__ src,
                          const int* __restrict__ dst, const float* __restrict__ dinv,
                          float* __restrict__ agg) {
    int gid = blockIdx.x * blockDim.x + threadIdx.x;  // exact grid: N_EDGES*32
    int e = gid >> 5;
    int c = gid & 31;
    int s = src[e], d = dst[e];
    float nrm = dinv[s] * dinv[d];
    float4 v = ((const float4*)(t + (size_t)s * HID_DIM))[c];
    float* o = agg + (size_t)d * HID_DIM + c * 4;
    atomicAdd(o + 0, v.x * nrm);
    atomicAdd(o + 1, v.y * nrm);
    atomicAdd(o + 2, v.z * nrm);
    atomicAdd(o + 3, v.w * nrm);
}

__global__ void k_bias_relu(float* __restrict__ h, const float* __restrict__ b) {
    int i = blockIdx.x * blockDim.x + threadIdx.x;    // exact grid: N_NODES*32
    int c = i & 31;
    float4 bv = ((const float4*)b)[c];
    float4 v = ((float4*)h)[i];
    v.x = fmaxf(v.x + bv.x, 0.f);
    v.y = fmaxf(v.y + bv.y, 0.f);
    v.z = fmaxf(v.z + bv.z, 0.f);
    v.w = fmaxf(v.w + bv.w, 0.f);
    ((float4*)h)[i] = v;
}

// ---------------- pooling + head ----------------

__global__ void k_pool(const float* __restrict__ h, const int* __restrict__ batch,
                       float* __restrict__ psum, int* __restrict__ cnt) {
    int i = blockIdx.x * blockDim.x + threadIdx.x;    // exact grid: N_NODES*32
    int m = i >> 5, c = i & 31;
    int g = batch[m];
    float4 v = ((const float4*)h)[i];
    float* p = psum + g * HID_DIM + c * 4;
    atomicAdd(p + 0, v.x);
    atomicAdd(p + 1, v.y);
    atomicAdd(p + 2, v.z);
    atomicAdd(p + 3, v.w);
    if (c == 0) atomicAdd(&cnt[g], 1);
}

__global__ void k_final(const float* __restrict__ psum, const int* __restrict__ cnt,
                        const float* __restrict__ fcw, const float* __restrict__ fcb,
                        float* __restrict__ out) {
    int g = blockIdx.x;
    int f = threadIdx.x;
    __shared__ float p[HID_DIM];
    float c = fmaxf((float)cnt[g], 1.f);
    p[f] = psum[g * HID_DIM + f] / c;
    __syncthreads();
    if (f < OUT_DIM) {
        float a = fcb[f];
        for (int k = 0; k < HID_DIM; k++) a = fmaf(p[k], fcw[f * HID_DIM + k], a);
        out[g * OUT_DIM + f] = a;
    }
}

// ---------------- launch ----------------

extern "C" void kernel_launch(void* const* d_in, const int* in_sizes, int n_in,
                              void* d_out, int out_size, void* d_ws, size_t ws_size,
                              hipStream_t stream) {
    const float* x   = (const float*)d_in[0];
    const int*  eidx = (const int*)d_in[1];
    const int* batch = (const int*)d_in[2];
    const float* w1  = (const float*)d_in[3];
    const float* b1  = (const float*)d_in[4];
    const float* w2  = (const float*)d_in[5];
    const float* b2  = (const float*)d_in[6];
    const float* fcw = (const float*)d_in[7];
    const float* fcb = (const float*)d_in[8];
    float* out = (float*)d_out;
    const int* src = eidx;             // edge_index[0]
    const int* dst = eidx + N_EDGES;   // edge_index[1]

    char* w = (char*)d_ws;
    float* bufA = (float*)(w);                 // 50000*128*4 = 25,600,000 B
    float* bufB = (float*)(w + 25600000);      // 25,600,000 B
    int*   degi = (int*)  (w + 51200000);      // 200,000 B (padded)
    float* dinv = (float*)(w + 51400192);      // 200,000 B (padded)
    float* psum = (float*)(w + 51600384);      // 32,768 B
    int*   cnt  = (int*)  (w + 51633152);      // 256 B

    dim3 b256(256);

    k_init<<<dim3((N_NODES + 255) / 256), b256, 0, stream>>>(degi, psum, cnt);
    k_degcount<<<dim3((N_EDGES + 255) / 256), b256, 0, stream>>>(dst, degi);
    k_dinv<<<dim3((N_NODES + 255) / 256), b256, 0, stream>>>(degi, dinv);

    // layer 1: t1 = x @ W1^T -> A ; agg -> B ; h1 = relu(B + b1) in place
    k_gemm_nt<IN_DIM><<<dim3((N_NODES + 63) / 64), b256, 0, stream>>>(x, w1, bufA);
    k_agg_init<<<dim3(N_NODES * 32 / 256), b256, 0, stream>>>(bufA, dinv, bufB);
    k_scatter<<<dim3(N_EDGES * 32 / 256), b256, 0, stream>>>(bufA, src, dst, dinv, bufB);
    k_bias_relu<<<dim3(N_NODES * 32 / 256), b256, 0, stream>>>(bufB, b1);

    // layer 2: t2 = h1 @ W2^T -> A ; agg -> B ; h2 = relu(B + b2) in place
    k_gemm_nt<HID_DIM><<<dim3((N_NODES + 63) / 64), b256, 0, stream>>>(bufB, w2, bufA);
    k_agg_init<<<dim3(N_NODES * 32 / 256), b256, 0, stream>>>(bufA, dinv, bufB);
    k_scatter<<<dim3(N_EDGES * 32 / 256), b256, 0, stream>>>(bufA, src, dst, dinv, bufB);
    k_bias_relu<<<dim3(N_NODES * 32 / 256), b256, 0, stream>>>(bufB, b2);

    // pool + head
    k_pool<<<dim3(N_NODES * 32 / 256), b256, 0, stream>>>(bufB, batch, psum, cnt);
    k_final<<<dim3(N_GRAPHS), dim3(HID_DIM), 0, stream>>>(psum, cnt, fcw, fcb, out);
}

// Round 2
// 791.162 us; speedup vs baseline: 4.1385x; 4.1385x over previous
//
#include <hip/hip_runtime.h>

#define N_NODES 50000
#define N_EDGES 800000
#define IN_DIM 64
#define HID_DIM 128
#define OUT_DIM 10
#define N_GRAPHS 64

// ---------------- init / degree ----------------

__global__ void k_init(int* __restrict__ deg, float* __restrict__ psum, int* __restrict__ cnt) {
    int i = blockIdx.x * blockDim.x + threadIdx.x;
    if (i < N_NODES) deg[i] = 0;                  // in-edges only; +1 self-loop added in k_scan
    if (i < N_GRAPHS * HID_DIM) psum[i] = 0.f;
    if (i < N_GRAPHS) cnt[i] = 0;
}

__global__ void k_degcount(const int* __restrict__ dst, int* __restrict__ deg) {
    int e = blockIdx.x * blockDim.x + threadIdx.x;
    if (e < N_EDGES) atomicAdd(&deg[dst[e]], 1);
}

// single-block exclusive scan of deg -> row_ptr (+cursor copy), dinv = rsqrt(deg+1)
__global__ __launch_bounds__(1024) void k_scan(const int* __restrict__ deg,
                                               int* __restrict__ row_ptr,
                                               int* __restrict__ cursor,
                                               float* __restrict__ dinv) {
    __shared__ int part[1024];
    const int t = threadIdx.x;
    const int CH = 49;                       // 49*1024 = 50176 >= 50000
    int lo = t * CH, hi = lo + CH; if (hi > N_NODES) hi = N_NODES;
    int s = 0;
    for (int i = lo; i < hi; i++) s += deg[i];
    part[t] = s;
    __syncthreads();
    for (int off = 1; off < 1024; off <<= 1) {
        int v = (t >= off) ? part[t - off] : 0;
        __syncthreads();
        part[t] += v;
        __syncthreads();
    }
    int run = (t > 0) ? part[t - 1] : 0;
    for (int i = lo; i < hi; i++) {
        row_ptr[i] = run;
        cursor[i] = run;
        run += deg[i];
        dinv[i] = rsqrtf((float)(deg[i] + 1));
    }
    if (t == 0) row_ptr[N_NODES] = N_EDGES;
}

// fill CSR adjacency: col[slot] = src of each in-edge of dst
__global__ void k_fill(const int* __restrict__ src, const int* __restrict__ dst,
                       int* __restrict__ cursor, int* __restrict__ col) {
    int e = blockIdx.x * blockDim.x + threadIdx.x;
    if (e < N_EDGES) {
        int d = dst[e];
        int p = atomicAdd(&cursor[d], 1);
        col[p] = src[e];
    }
}

// ---------------- GEMM: O[m][n] = sum_k X[m][k] * W[n][k], N=128 ----------------

template<int K>
__global__ __launch_bounds__(256) void k_gemm_nt(const float* __restrict__ X,
                                                 const float* __restrict__ W,
                                                 float* __restrict__ O) {
    constexpr int KC = 64;
    __shared__ float wsT[KC * 132];
    __shared__ float xsT[KC * 68];
    const int tid = threadIdx.x;
    const int bm = blockIdx.x * 64;
    const int fg = tid & 31;
    const int ng = tid >> 5;

    float acc[8][4];
#pragma unroll
    for (int i = 0; i < 8; i++)
#pragma unroll
        for (int j = 0; j < 4; j++) acc[i][j] = 0.f;

    for (int k0 = 0; k0 < K; k0 += KC) {
        for (int i = tid; i < HID_DIM * KC; i += 256) {
            int n = i >> 6, k = i & 63;
            wsT[k * 132 + n] = W[n * K + k0 + k];
        }
        for (int i = tid; i < 64 * KC; i += 256) {
            int r = i >> 6, k = i & 63;
            int m = bm + r;
            xsT[k * 68 + r] = (m < N_NODES) ? X[(size_t)m * K + k0 + k] : 0.f;
        }
        __syncthreads();
#pragma unroll 4
        for (int k = 0; k < KC; k++) {
            const float4 w4 = *(const float4*)&wsT[k * 132 + 4 * fg];
            const float4 xa = *(const float4*)&xsT[k * 68 + 8 * ng];
            const float4 xb = *(const float4*)&xsT[k * 68 + 8 * ng + 4];
            float xv[8] = {xa.x, xa.y, xa.z, xa.w, xb.x, xb.y, xb.z, xb.w};
            float wv[4] = {w4.x, w4.y, w4.z, w4.w};
#pragma unroll
            for (int i = 0; i < 8; i++)
#pragma unroll
                for (int j = 0; j < 4; j++)
                    acc[i][j] = fmaf(xv[i], wv[j], acc[i][j]);
        }
        __syncthreads();
    }
#pragma unroll
    for (int i = 0; i < 8; i++) {
        int m = bm + 8 * ng + i;
        if (m < N_NODES)
            *(float4*)&O[(size_t)m * HID_DIM + 4 * fg] =
                make_float4(acc[i][0], acc[i][1], acc[i][2], acc[i][3]);
    }
}

// ---------------- fused gather + self-loop + bias + relu ----------------
// out[d] = relu( dinv[d] * ( dinv[d]*t[d] + sum_{s in N(d)} dinv[s]*t[s] ) + b )
// 32-lane group per node, lane c owns float4 chunk c (128 floats = 32 chunks).

__global__ __launch_bounds__(256) void k_gather(const float* __restrict__ t,
                                                const int* __restrict__ row_ptr,
                                                const int* __restrict__ col,
                                                const float* __restrict__ dinv,
                                                const float* __restrict__ bias,
                                                float* __restrict__ out) {
    const int g = blockIdx.x * 8 + (threadIdx.x >> 5);   // grid 6250*8 = 50000 exact
    const int c = threadIdx.x & 31;
    const float4* __restrict__ t4 = (const float4*)t;

    const float dm = dinv[g];
    float4 v = t4[(size_t)g * 32 + c];
    float ax = dm * v.x, ay = dm * v.y, az = dm * v.z, aw = dm * v.w;

    const int beg = row_ptr[g], end = row_ptr[g + 1];
    for (int j = beg; j < end; j++) {
        int s = col[j];
        float ds = dinv[s];
        float4 u = t4[(size_t)s * 32 + c];
        ax = fmaf(ds, u.x, ax);
        ay = fmaf(ds, u.y, ay);
        az = fmaf(ds, u.z, az);
        aw = fmaf(ds, u.w, aw);
    }
    float4 b = ((const float4*)bias)[c];
    float4 o;
    o.x = fmaxf(fmaf(dm, ax, b.x), 0.f);
    o.y = fmaxf(fmaf(dm, ay, b.y), 0.f);
    o.z = fmaxf(fmaf(dm, az, b.z), 0.f);
    o.w = fmaxf(fmaf(dm, aw, b.w), 0.f);
    ((float4*)out)[(size_t)g * 32 + c] = o;
}

// ---------------- pooling + head ----------------

__global__ void k_pool(const float* __restrict__ h, const int* __restrict__ batch,
                       float* __restrict__ psum, int* __restrict__ cnt) {
    int i = blockIdx.x * blockDim.x + threadIdx.x;    // exact grid: N_NODES*32
    int m = i >> 5, c = i & 31;
    int g = batch[m];
    float4 v = ((const float4*)h)[i];
    float* p = psum + g * HID_DIM + c * 4;
    atomicAdd(p + 0, v.x);
    atomicAdd(p + 1, v.y);
    atomicAdd(p + 2, v.z);
    atomicAdd(p + 3, v.w);
    if (c == 0) atomicAdd(&cnt[g], 1);
}

__global__ void k_final(const float* __restrict__ psum, const int* __restrict__ cnt,
                        const float* __restrict__ fcw, const float* __restrict__ fcb,
                        float* __restrict__ out) {
    int g = blockIdx.x;
    int f = threadIdx.x;
    __shared__ float p[HID_DIM];
    float c = fmaxf((float)cnt[g], 1.f);
    p[f] = psum[g * HID_DIM + f] / c;
    __syncthreads();
    if (f < OUT_DIM) {
        float a = fcb[f];
        for (int k = 0; k < HID_DIM; k++) a = fmaf(p[k], fcw[f * HID_DIM + k], a);
        out[g * OUT_DIM + f] = a;
    }
}

// ---------------- launch ----------------

extern "C" void kernel_launch(void* const* d_in, const int* in_sizes, int n_in,
                              void* d_out, int out_size, void* d_ws, size_t ws_size,
                              hipStream_t stream) {
    const float* x   = (const float*)d_in[0];
    const int*  eidx = (const int*)d_in[1];
    const int* batch = (const int*)d_in[2];
    const float* w1  = (const float*)d_in[3];
    const float* b1  = (const float*)d_in[4];
    const float* w2  = (const float*)d_in[5];
    const float* b2  = (const float*)d_in[6];
    const float* fcw = (const float*)d_in[7];
    const float* fcb = (const float*)d_in[8];
    float* out = (float*)d_out;
    const int* src = eidx;             // edge_index[0]
    const int* dst = eidx + N_EDGES;   // edge_index[1]

    char* w = (char*)d_ws;
    float* bufA    = (float*)(w);                 // 25,600,000 B
    float* bufB    = (float*)(w + 25600000);      // 25,600,000 B
    int*   deg     = (int*)  (w + 51200000);      // 200,000 B
    int*   row_ptr = (int*)  (w + 51400000);      // 200,064 B (50001 ints)
    int*   cursor  = (int*)  (w + 51600064);      // 200,000 B
    float* dinv    = (float*)(w + 51800064);      // 200,000 B
    int*   col     = (int*)  (w + 52000064);      // 3,200,000 B
    float* psum    = (float*)(w + 55200064);      // 32,768 B
    int*   cnt     = (int*)  (w + 55232832);      // 256 B

    dim3 b256(256);

    // CSR build (graph static across both layers)
    k_init<<<dim3((N_NODES + 255) / 256), b256, 0, stream>>>(deg, psum, cnt);
    k_degcount<<<dim3((N_EDGES + 255) / 256), b256, 0, stream>>>(dst, deg);
    k_scan<<<dim3(1), dim3(1024), 0, stream>>>(deg, row_ptr, cursor, dinv);
    k_fill<<<dim3((N_EDGES + 255) / 256), b256, 0, stream>>>(src, dst, cursor, col);

    // layer 1: t1 = x @ W1^T -> A ; h1 = relu(gather(A) + b1) -> B
    k_gemm_nt<IN_DIM><<<dim3((N_NODES + 63) / 64), b256, 0, stream>>>(x, w1, bufA);
    k_gather<<<dim3(N_NODES / 8), b256, 0, stream>>>(bufA, row_ptr, col, dinv, b1, bufB);

    // layer 2: t2 = h1 @ W2^T -> A ; h2 = relu(gather(A) + b2) -> B
    k_gemm_nt<HID_DIM><<<dim3((N_NODES + 63) / 64), b256, 0, stream>>>(bufB, w2, bufA);
    k_gather<<<dim3(N_NODES / 8), b256, 0, stream>>>(bufA, row_ptr, col, dinv, b2, bufB);

    // pool + head
    k_pool<<<dim3(N_NODES * 32 / 256), b256, 0, stream>>>(bufB, batch, psum, cnt);
    k_final<<<dim3(N_GRAPHS), dim3(HID_DIM), 0, stream>>>(psum, cnt, fcw, fcb, out);
}

// Round 3
// 516.627 us; speedup vs baseline: 6.3377x; 1.5314x over previous
//
#include <hip/hip_runtime.h>

#define N_NODES 50000
#define N_EDGES 800000
#define IN_DIM 64
#define HID_DIM 128
#define OUT_DIM 10
#define N_GRAPHS 64

// ---------------- init / degree ----------------

__global__ void k_init(int* __restrict__ deg) {
    int i = blockIdx.x * blockDim.x + threadIdx.x;
    if (i < N_NODES) deg[i] = 0;                  // in-edges only; +1 self-loop added in k_scan
}

__global__ void k_degcount(const int* __restrict__ dst, int* __restrict__ deg) {
    int e = blockIdx.x * blockDim.x + threadIdx.x;
    if (e < N_EDGES) atomicAdd(&deg[dst[e]], 1);
}

// graph boundaries from sorted batch: gstart[g] = first node of graph g, gstart[64] = N
__global__ void k_bounds(const int* __restrict__ batch, int* __restrict__ gstart) {
    int m = blockIdx.x * blockDim.x + threadIdx.x;
    if (m >= N_NODES) return;
    int b = batch[m];
    if (m == 0) {
        for (int g = 0; g <= b; g++) gstart[g] = 0;
    } else {
        int a = batch[m - 1];
        for (int g = a + 1; g <= b; g++) gstart[g] = m;
    }
    if (m == N_NODES - 1) {
        for (int g = b + 1; g <= N_GRAPHS; g++) gstart[g] = N_NODES;
    }
}

// single-block exclusive scan of deg -> row_ptr (+cursor copy), dinv = rsqrt(deg+1)
__global__ __launch_bounds__(1024) void k_scan(const int* __restrict__ deg,
                                               int* __restrict__ row_ptr,
                                               int* __restrict__ cursor,
                                               float* __restrict__ dinv) {
    __shared__ int part[1024];
    const int t = threadIdx.x;
    const int CH = 49;                       // 49*1024 = 50176 >= 50000
    int lo = t * CH, hi = lo + CH; if (hi > N_NODES) hi = N_NODES;
    int s = 0;
    for (int i = lo; i < hi; i++) s += deg[i];
    part[t] = s;
    __syncthreads();
    for (int off = 1; off < 1024; off <<= 1) {
        int v = (t >= off) ? part[t - off] : 0;
        __syncthreads();
        part[t] += v;
        __syncthreads();
    }
    int run = (t > 0) ? part[t - 1] : 0;
    for (int i = lo; i < hi; i++) {
        row_ptr[i] = run;
        cursor[i] = run;
        run += deg[i];
        dinv[i] = rsqrtf((float)(deg[i] + 1));
    }
    if (t == 0) row_ptr[N_NODES] = N_EDGES;
}

// fill CSR adjacency: col[slot] = src of each in-edge of dst
__global__ void k_fill(const int* __restrict__ src, const int* __restrict__ dst,
                       int* __restrict__ cursor, int* __restrict__ col) {
    int e = blockIdx.x * blockDim.x + threadIdx.x;
    if (e < N_EDGES) {
        int d = dst[e];
        int p = atomicAdd(&cursor[d], 1);
        col[p] = src[e];
    }
}

// ---------------- GEMM: O[m][n] = sum_k X[m][k] * W[n][k], N=128 ----------------

template<int K>
__global__ __launch_bounds__(256) void k_gemm_nt(const float* __restrict__ X,
                                                 const float* __restrict__ W,
                                                 float* __restrict__ O) {
    constexpr int KC = 64;
    __shared__ float wsT[KC * 132];
    __shared__ float xsT[KC * 68];
    const int tid = threadIdx.x;
    const int bm = blockIdx.x * 64;
    const int fg = tid & 31;
    const int ng = tid >> 5;

    float acc[8][4];
#pragma unroll
    for (int i = 0; i < 8; i++)
#pragma unroll
        for (int j = 0; j < 4; j++) acc[i][j] = 0.f;

    for (int k0 = 0; k0 < K; k0 += KC) {
        for (int i = tid; i < HID_DIM * KC; i += 256) {
            int n = i >> 6, k = i & 63;
            wsT[k * 132 + n] = W[n * K + k0 + k];
        }
        for (int i = tid; i < 64 * KC; i += 256) {
            int r = i >> 6, k = i & 63;
            int m = bm + r;
            xsT[k * 68 + r] = (m < N_NODES) ? X[(size_t)m * K + k0 + k] : 0.f;
        }
        __syncthreads();
#pragma unroll 4
        for (int k = 0; k < KC; k++) {
            const float4 w4 = *(const float4*)&wsT[k * 132 + 4 * fg];
            const float4 xa = *(const float4*)&xsT[k * 68 + 8 * ng];
            const float4 xb = *(const float4*)&xsT[k * 68 + 8 * ng + 4];
            float xv[8] = {xa.x, xa.y, xa.z, xa.w, xb.x, xb.y, xb.z, xb.w};
            float wv[4] = {w4.x, w4.y, w4.z, w4.w};
#pragma unroll
            for (int i = 0; i < 8; i++)
#pragma unroll
                for (int j = 0; j < 4; j++)
                    acc[i][j] = fmaf(xv[i], wv[j], acc[i][j]);
        }
        __syncthreads();
    }
#pragma unroll
    for (int i = 0; i < 8; i++) {
        int m = bm + 8 * ng + i;
        if (m < N_NODES)
            *(float4*)&O[(size_t)m * HID_DIM + 4 * fg] =
                make_float4(acc[i][0], acc[i][1], acc[i][2], acc[i][3]);
    }
}

// ---------------- fused gather + self-loop + bias + relu ----------------
// out[d] = relu( dinv[d] * ( dinv[d]*t[d] + sum_{s in N(d)} dinv[s]*t[s] ) + b )

__global__ __launch_bounds__(256) void k_gather(const float* __restrict__ t,
                                                const int* __restrict__ row_ptr,
                                                const int* __restrict__ col,
                                                const float* __restrict__ dinv,
                                                const float* __restrict__ bias,
                                                float* __restrict__ out) {
    const int g = blockIdx.x * 8 + (threadIdx.x >> 5);   // grid 6250*8 = 50000 exact
    const int c = threadIdx.x & 31;
    const float4* __restrict__ t4 = (const float4*)t;

    const float dm = dinv[g];
    float4 v = t4[(size_t)g * 32 + c];
    float ax = dm * v.x, ay = dm * v.y, az = dm * v.z, aw = dm * v.w;

    const int beg = row_ptr[g], end = row_ptr[g + 1];
    for (int j = beg; j < end; j++) {
        int s = col[j];
        float ds = dinv[s];
        float4 u = t4[(size_t)s * 32 + c];
        ax = fmaf(ds, u.x, ax);
        ay = fmaf(ds, u.y, ay);
        az = fmaf(ds, u.z, az);
        aw = fmaf(ds, u.w, aw);
    }
    float4 b = ((const float4*)bias)[c];
    float4 o;
    o.x = fmaxf(fmaf(dm, ax, b.x), 0.f);
    o.y = fmaxf(fmaf(dm, ay, b.y), 0.f);
    o.z = fmaxf(fmaf(dm, az, b.z), 0.f);
    o.w = fmaxf(fmaf(dm, aw, b.w), 0.f);
    ((float4*)out)[(size_t)g * 32 + c] = o;
}

// ---------------- fused mean-pool + FC head ----------------
// one block per graph; 256 threads = 2 node-streams x 128 features

__global__ __launch_bounds__(256) void k_pool_fc(const float* __restrict__ h,
                                                 const int* __restrict__ gstart,
                                                 const float* __restrict__ fcw,
                                                 const float* __restrict__ fcb,
                                                 float* __restrict__ out) {
    const int g = blockIdx.x;
    const int f = threadIdx.x & 127;
    const int s = threadIdx.x >> 7;        // 0 or 1
    const int beg = gstart[g], end = gstart[g + 1];

    float acc = 0.f;
#pragma unroll 4
    for (int m = beg + s; m < end; m += 2)
        acc += h[(size_t)m * HID_DIM + f];

    __shared__ float tmp[256];
    __shared__ float pool[HID_DIM];
    tmp[threadIdx.x] = acc;
    __syncthreads();
    if (s == 0) {
        float tot = tmp[f] + tmp[128 + f];
        float c = fmaxf((float)(end - beg), 1.f);
        pool[f] = tot / c;
    }
    __syncthreads();
    if (threadIdx.x < OUT_DIM) {
        float a = fcb[threadIdx.x];
#pragma unroll 8
        for (int k = 0; k < HID_DIM; k++)
            a = fmaf(pool[k], fcw[threadIdx.x * HID_DIM + k], a);
        out[g * OUT_DIM + threadIdx.x] = a;
    }
}

// ---------------- launch ----------------

extern "C" void kernel_launch(void* const* d_in, const int* in_sizes, int n_in,
                              void* d_out, int out_size, void* d_ws, size_t ws_size,
                              hipStream_t stream) {
    const float* x   = (const float*)d_in[0];
    const int*  eidx = (const int*)d_in[1];
    const int* batch = (const int*)d_in[2];
    const float* w1  = (const float*)d_in[3];
    const float* b1  = (const float*)d_in[4];
    const float* w2  = (const float*)d_in[5];
    const float* b2  = (const float*)d_in[6];
    const float* fcw = (const float*)d_in[7];
    const float* fcb = (const float*)d_in[8];
    float* out = (float*)d_out;
    const int* src = eidx;             // edge_index[0]
    const int* dst = eidx + N_EDGES;   // edge_index[1]

    char* w = (char*)d_ws;
    float* bufA    = (float*)(w);                 // 25,600,000 B
    float* bufB    = (float*)(w + 25600000);      // 25,600,000 B
    int*   deg     = (int*)  (w + 51200000);      // 200,000 B
    int*   row_ptr = (int*)  (w + 51400000);      // 200,064 B (50001 ints)
    int*   cursor  = (int*)  (w + 51600064);      // 200,000 B
    float* dinv    = (float*)(w + 51800064);      // 200,000 B
    int*   col     = (int*)  (w + 52000064);      // 3,200,000 B
    int*   gstart  = (int*)  (w + 55200064);      // 260 B (65 ints)

    dim3 b256(256);

    // CSR build (graph static across both layers) + graph boundaries
    k_init<<<dim3((N_NODES + 255) / 256), b256, 0, stream>>>(deg);
    k_degcount<<<dim3((N_EDGES + 255) / 256), b256, 0, stream>>>(dst, deg);
    k_bounds<<<dim3((N_NODES + 255) / 256), b256, 0, stream>>>(batch, gstart);
    k_scan<<<dim3(1), dim3(1024), 0, stream>>>(deg, row_ptr, cursor, dinv);
    k_fill<<<dim3((N_EDGES + 255) / 256), b256, 0, stream>>>(src, dst, cursor, col);

    // layer 1: t1 = x @ W1^T -> A ; h1 = relu(gather(A) + b1) -> B
    k_gemm_nt<IN_DIM><<<dim3((N_NODES + 63) / 64), b256, 0, stream>>>(x, w1, bufA);
    k_gather<<<dim3(N_NODES / 8), b256, 0, stream>>>(bufA, row_ptr, col, dinv, b1, bufB);

    // layer 2: t2 = h1 @ W2^T -> A ; h2 = relu(gather(A) + b2) -> B
    k_gemm_nt<HID_DIM><<<dim3((N_NODES + 63) / 64), b256, 0, stream>>>(bufB, w2, bufA);
    k_gather<<<dim3(N_NODES / 8), b256, 0, stream>>>(bufA, row_ptr, col, dinv, b2, bufB);

    // fused mean-pool + FC head
    k_pool_fc<<<dim3(N_GRAPHS), b256, 0, stream>>>(bufB, gstart, fcw, fcb, out);
}

// Round 4
// 394.666 us; speedup vs baseline: 8.2961x; 1.3090x over previous
//
#include <hip/hip_runtime.h>

#define N_NODES 50000
#define N_EDGES 800000
#define IN_DIM 64
#define HID_DIM 128
#define OUT_DIM 10
#define N_GRAPHS 64

#define SCAN_BLOCKS ((N_NODES + 255) / 256)   // 196

// ---------------- init / degree ----------------

__global__ void k_init(int* __restrict__ deg) {
    int i = blockIdx.x * blockDim.x + threadIdx.x;
    if (i < N_NODES) deg[i] = 0;                  // in-edges only; +1 self-loop in dinv
}

__global__ void k_degcount(const int* __restrict__ dst, int* __restrict__ deg) {
    int e = blockIdx.x * blockDim.x + threadIdx.x;
    if (e < N_EDGES) atomicAdd(&deg[dst[e]], 1);
}

// graph boundaries from sorted batch: gstart[g] = first node of graph g, gstart[64] = N
__global__ void k_bounds(const int* __restrict__ batch, int* __restrict__ gstart) {
    int m = blockIdx.x * blockDim.x + threadIdx.x;
    if (m >= N_NODES) return;
    int b = batch[m];
    if (m == 0) {
        for (int g = 0; g <= b; g++) gstart[g] = 0;
    } else {
        int a = batch[m - 1];
        for (int g = a + 1; g <= b; g++) gstart[g] = m;
    }
    if (m == N_NODES - 1) {
        for (int g = b + 1; g <= N_GRAPHS; g++) gstart[g] = N_NODES;
    }
}

// ---------------- 3-phase parallel scan of deg -> row_ptr ----------------

// phase 1: per-block sum of deg (256-wide) -> bsum; also dinv = rsqrt(deg+1)
__global__ __launch_bounds__(256) void k_scan1(const int* __restrict__ deg,
                                               int* __restrict__ bsum,
                                               float* __restrict__ dinv) {
    __shared__ int red[256];
    int i = blockIdx.x * 256 + threadIdx.x;
    int d = (i < N_NODES) ? deg[i] : 0;
    if (i < N_NODES) dinv[i] = rsqrtf((float)(d + 1));
    red[threadIdx.x] = d;
    __syncthreads();
#pragma unroll
    for (int off = 128; off > 0; off >>= 1) {
        if (threadIdx.x < off) red[threadIdx.x] += red[threadIdx.x + off];
        __syncthreads();
    }
    if (threadIdx.x == 0) bsum[blockIdx.x] = red[0];
}

// phase 2: single small block scans the 196 block sums -> exclusive boff
__global__ __launch_bounds__(256) void k_scan2(const int* __restrict__ bsum,
                                               int* __restrict__ boff) {
    __shared__ int s[256];
    int t = threadIdx.x;
    s[t] = (t < SCAN_BLOCKS) ? bsum[t] : 0;
    __syncthreads();
#pragma unroll
    for (int off = 1; off < 256; off <<= 1) {
        int v = (t >= off) ? s[t - off] : 0;
        __syncthreads();
        s[t] += v;
        __syncthreads();
    }
    if (t < SCAN_BLOCKS) boff[t] = (t > 0) ? s[t - 1] : 0;
}

// phase 3: per-block local exclusive scan + block offset -> row_ptr, cursor
__global__ __launch_bounds__(256) void k_scan3(const int* __restrict__ deg,
                                               const int* __restrict__ boff,
                                               int* __restrict__ row_ptr,
                                               int* __restrict__ cursor) {
    __shared__ int s[256];
    int t = threadIdx.x;
    int i = blockIdx.x * 256 + t;
    int d = (i < N_NODES) ? deg[i] : 0;
    s[t] = d;
    __syncthreads();
#pragma unroll
    for (int off = 1; off < 256; off <<= 1) {
        int v = (t >= off) ? s[t - off] : 0;
        __syncthreads();
        s[t] += v;
        __syncthreads();
    }
    if (i < N_NODES) {
        int excl = boff[blockIdx.x] + s[t] - d;   // inclusive - self = exclusive
        row_ptr[i] = excl;
        cursor[i] = excl;
    }
    if (i == 0) row_ptr[N_NODES] = N_EDGES;
}

// fill CSR adjacency: col[slot] = src of each in-edge of dst
__global__ void k_fill(const int* __restrict__ src, const int* __restrict__ dst,
                       int* __restrict__ cursor, int* __restrict__ col) {
    int e = blockIdx.x * blockDim.x + threadIdx.x;
    if (e < N_EDGES) {
        int d = dst[e];
        int p = atomicAdd(&cursor[d], 1);
        col[p] = src[e];
    }
}

// ---------------- GEMM: O[m][n] = sum_k X[m][k] * W[n][k], N=128 ----------------

template<int K>
__global__ __launch_bounds__(256) void k_gemm_nt(const float* __restrict__ X,
                                                 const float* __restrict__ W,
                                                 float* __restrict__ O) {
    constexpr int KC = 64;
    __shared__ float wsT[KC * 132];
    __shared__ float xsT[KC * 68];
    const int tid = threadIdx.x;
    const int bm = blockIdx.x * 64;
    const int fg = tid & 31;
    const int ng = tid >> 5;

    float acc[8][4];
#pragma unroll
    for (int i = 0; i < 8; i++)
#pragma unroll
        for (int j = 0; j < 4; j++) acc[i][j] = 0.f;

    for (int k0 = 0; k0 < K; k0 += KC) {
        for (int i = tid; i < HID_DIM * KC; i += 256) {
            int n = i >> 6, k = i & 63;
            wsT[k * 132 + n] = W[n * K + k0 + k];
        }
        for (int i = tid; i < 64 * KC; i += 256) {
            int r = i >> 6, k = i & 63;
            int m = bm + r;
            xsT[k * 68 + r] = (m < N_NODES) ? X[(size_t)m * K + k0 + k] : 0.f;
        }
        __syncthreads();
#pragma unroll 4
        for (int k = 0; k < KC; k++) {
            const float4 w4 = *(const float4*)&wsT[k * 132 + 4 * fg];
            const float4 xa = *(const float4*)&xsT[k * 68 + 8 * ng];
            const float4 xb = *(const float4*)&xsT[k * 68 + 8 * ng + 4];
            float xv[8] = {xa.x, xa.y, xa.z, xa.w, xb.x, xb.y, xb.z, xb.w};
            float wv[4] = {w4.x, w4.y, w4.z, w4.w};
#pragma unroll
            for (int i = 0; i < 8; i++)
#pragma unroll
                for (int j = 0; j < 4; j++)
                    acc[i][j] = fmaf(xv[i], wv[j], acc[i][j]);
        }
        __syncthreads();
    }
#pragma unroll
    for (int i = 0; i < 8; i++) {
        int m = bm + 8 * ng + i;
        if (m < N_NODES)
            *(float4*)&O[(size_t)m * HID_DIM + 4 * fg] =
                make_float4(acc[i][0], acc[i][1], acc[i][2], acc[i][3]);
    }
}

// ---------------- fused gather + self-loop + bias + relu ----------------
// out[d] = relu( dinv[d] * ( dinv[d]*t[d] + sum_{s in N(d)} dinv[s]*t[s] ) + b )

__global__ __launch_bounds__(256) void k_gather(const float* __restrict__ t,
                                                const int* __restrict__ row_ptr,
                                                const int* __restrict__ col,
                                                const float* __restrict__ dinv,
                                                const float* __restrict__ bias,
                                                float* __restrict__ out) {
    const int g = blockIdx.x * 8 + (threadIdx.x >> 5);   // grid 6250*8 = 50000 exact
    const int c = threadIdx.x & 31;
    const float4* __restrict__ t4 = (const float4*)t;

    const float dm = dinv[g];
    float4 v = t4[(size_t)g * 32 + c];
    float ax = dm * v.x, ay = dm * v.y, az = dm * v.z, aw = dm * v.w;

    const int beg = row_ptr[g], end = row_ptr[g + 1];
    for (int j = beg; j < end; j++) {
        int s = col[j];
        float ds = dinv[s];
        float4 u = t4[(size_t)s * 32 + c];
        ax = fmaf(ds, u.x, ax);
        ay = fmaf(ds, u.y, ay);
        az = fmaf(ds, u.z, az);
        aw = fmaf(ds, u.w, aw);
    }
    float4 b = ((const float4*)bias)[c];
    float4 o;
    o.x = fmaxf(fmaf(dm, ax, b.x), 0.f);
    o.y = fmaxf(fmaf(dm, ay, b.y), 0.f);
    o.z = fmaxf(fmaf(dm, az, b.z), 0.f);
    o.w = fmaxf(fmaf(dm, aw, b.w), 0.f);
    ((float4*)out)[(size_t)g * 32 + c] = o;
}

// ---------------- fused mean-pool + FC head ----------------

__global__ __launch_bounds__(256) void k_pool_fc(const float* __restrict__ h,
                                                 const int* __restrict__ gstart,
                                                 const float* __restrict__ fcw,
                                                 const float* __restrict__ fcb,
                                                 float* __restrict__ out) {
    const int g = blockIdx.x;
    const int f = threadIdx.x & 127;
    const int s = threadIdx.x >> 7;        // 0 or 1
    const int beg = gstart[g], end = gstart[g + 1];

    float acc = 0.f;
#pragma unroll 4
    for (int m = beg + s; m < end; m += 2)
        acc += h[(size_t)m * HID_DIM + f];

    __shared__ float tmp[256];
    __shared__ float pool[HID_DIM];
    tmp[threadIdx.x] = acc;
    __syncthreads();
    if (s == 0) {
        float tot = tmp[f] + tmp[128 + f];
        float c = fmaxf((float)(end - beg), 1.f);
        pool[f] = tot / c;
    }
    __syncthreads();
    if (threadIdx.x < OUT_DIM) {
        float a = fcb[threadIdx.x];
#pragma unroll 8
        for (int k = 0; k < HID_DIM; k++)
            a = fmaf(pool[k], fcw[threadIdx.x * HID_DIM + k], a);
        out[g * OUT_DIM + threadIdx.x] = a;
    }
}

// ---------------- launch ----------------

extern "C" void kernel_launch(void* const* d_in, const int* in_sizes, int n_in,
                              void* d_out, int out_size, void* d_ws, size_t ws_size,
                              hipStream_t stream) {
    const float* x   = (const float*)d_in[0];
    const int*  eidx = (const int*)d_in[1];
    const int* batch = (const int*)d_in[2];
    const float* w1  = (const float*)d_in[3];
    const float* b1  = (const float*)d_in[4];
    const float* w2  = (const float*)d_in[5];
    const float* b2  = (const float*)d_in[6];
    const float* fcw = (const float*)d_in[7];
    const float* fcb = (const float*)d_in[8];
    float* out = (float*)d_out;
    const int* src = eidx;             // edge_index[0]
    const int* dst = eidx + N_EDGES;   // edge_index[1]

    char* w = (char*)d_ws;
    float* bufA    = (float*)(w);                 // 25,600,000 B
    float* bufB    = (float*)(w + 25600000);      // 25,600,000 B
    int*   deg     = (int*)  (w + 51200000);      // 200,000 B
    int*   row_ptr = (int*)  (w + 51400000);      // 200,064 B (50001 ints)
    int*   cursor  = (int*)  (w + 51600064);      // 200,000 B
    float* dinv    = (float*)(w + 51800064);      // 200,000 B
    int*   col     = (int*)  (w + 52000064);      // 3,200,000 B
    int*   gstart  = (int*)  (w + 55200064);      // 260 B (65 ints)
    int*   bsum    = (int*)  (w + 55200384);      // 1024 B (196 ints, padded)
    int*   boff    = (int*)  (w + 55201408);      // 1024 B

    dim3 b256(256);

    // CSR build (graph static across both layers) + graph boundaries
    k_init<<<dim3((N_NODES + 255) / 256), b256, 0, stream>>>(deg);
    k_degcount<<<dim3((N_EDGES + 255) / 256), b256, 0, stream>>>(dst, deg);
    k_bounds<<<dim3((N_NODES + 255) / 256), b256, 0, stream>>>(batch, gstart);
    k_scan1<<<dim3(SCAN_BLOCKS), b256, 0, stream>>>(deg, bsum, dinv);
    k_scan2<<<dim3(1), b256, 0, stream>>>(bsum, boff);
    k_scan3<<<dim3(SCAN_BLOCKS), b256, 0, stream>>>(deg, boff, row_ptr, cursor);
    k_fill<<<dim3((N_EDGES + 255) / 256), b256, 0, stream>>>(src, dst, cursor, col);

    // layer 1: t1 = x @ W1^T -> A ; h1 = relu(gather(A) + b1) -> B
    k_gemm_nt<IN_DIM><<<dim3((N_NODES + 63) / 64), b256, 0, stream>>>(x, w1, bufA);
    k_gather<<<dim3(N_NODES / 8), b256, 0, stream>>>(bufA, row_ptr, col, dinv, b1, bufB);

    // layer 2: t2 = h1 @ W2^T -> A ; h2 = relu(gather(A) + b2) -> B
    k_gemm_nt<HID_DIM><<<dim3((N_NODES + 63) / 64), b256, 0, stream>>>(bufB, w2, bufA);
    k_gather<<<dim3(N_NODES / 8), b256, 0, stream>>>(bufA, row_ptr, col, dinv, b2, bufB);

    // fused mean-pool + FC head
    k_pool_fc<<<dim3(N_GRAPHS), b256, 0, stream>>>(bufB, gstart, fcw, fcb, out);
}

// Round 5
// 392.590 us; speedup vs baseline: 8.3400x; 1.0053x over previous
//
#include <hip/hip_runtime.h>

#define N_NODES 50000
#define N_EDGES 800000
#define IN_DIM 64
#define HID_DIM 128
#define OUT_DIM 10
#define N_GRAPHS 64

#define SCAN_BLOCKS ((N_NODES + 255) / 256)   // 196

// ---------------- degree / bounds ----------------

__global__ void k_degcount(const int* __restrict__ dst, int* __restrict__ deg) {
    int e = blockIdx.x * blockDim.x + threadIdx.x;
    if (e < N_EDGES) atomicAdd(&deg[dst[e]], 1);
}

// graph boundaries from sorted batch: gstart[g] = first node of graph g, gstart[64] = N
__global__ void k_bounds(const int* __restrict__ batch, int* __restrict__ gstart) {
    int m = blockIdx.x * blockDim.x + threadIdx.x;
    if (m >= N_NODES) return;
    int b = batch[m];
    if (m == 0) {
        for (int g = 0; g <= b; g++) gstart[g] = 0;
    } else {
        int a = batch[m - 1];
        for (int g = a + 1; g <= b; g++) gstart[g] = m;
    }
    if (m == N_NODES - 1) {
        for (int g = b + 1; g <= N_GRAPHS; g++) gstart[g] = N_NODES;
    }
}

// ---------------- 3-phase parallel scan of deg -> row_ptr ----------------

__global__ __launch_bounds__(256) void k_scan1(const int* __restrict__ deg,
                                               int* __restrict__ bsum,
                                               float* __restrict__ dinv) {
    __shared__ int red[256];
    int i = blockIdx.x * 256 + threadIdx.x;
    int d = (i < N_NODES) ? deg[i] : 0;
    if (i < N_NODES) dinv[i] = rsqrtf((float)(d + 1));
    red[threadIdx.x] = d;
    __syncthreads();
#pragma unroll
    for (int off = 128; off > 0; off >>= 1) {
        if (threadIdx.x < off) red[threadIdx.x] += red[threadIdx.x + off];
        __syncthreads();
    }
    if (threadIdx.x == 0) bsum[blockIdx.x] = red[0];
}

__global__ __launch_bounds__(256) void k_scan2(const int* __restrict__ bsum,
                                               int* __restrict__ boff) {
    __shared__ int s[256];
    int t = threadIdx.x;
    s[t] = (t < SCAN_BLOCKS) ? bsum[t] : 0;
    __syncthreads();
#pragma unroll
    for (int off = 1; off < 256; off <<= 1) {
        int v = (t >= off) ? s[t - off] : 0;
        __syncthreads();
        s[t] += v;
        __syncthreads();
    }
    if (t < SCAN_BLOCKS) boff[t] = (t > 0) ? s[t - 1] : 0;
}

__global__ __launch_bounds__(256) void k_scan3(const int* __restrict__ deg,
                                               const int* __restrict__ boff,
                                               int* __restrict__ row_ptr,
                                               int* __restrict__ cursor) {
    __shared__ int s[256];
    int t = threadIdx.x;
    int i = blockIdx.x * 256 + t;
    int d = (i < N_NODES) ? deg[i] : 0;
    s[t] = d;
    __syncthreads();
#pragma unroll
    for (int off = 1; off < 256; off <<= 1) {
        int v = (t >= off) ? s[t - off] : 0;
        __syncthreads();
        s[t] += v;
        __syncthreads();
    }
    if (i < N_NODES) {
        int excl = boff[blockIdx.x] + s[t] - d;
        row_ptr[i] = excl;
        cursor[i] = excl;
    }
    if (i == 0) row_ptr[N_NODES] = N_EDGES;
}

__global__ void k_fill(const int* __restrict__ src, const int* __restrict__ dst,
                       int* __restrict__ cursor, int* __restrict__ col) {
    int e = blockIdx.x * blockDim.x + threadIdx.x;
    if (e < N_EDGES) {
        int d = dst[e];
        int p = atomicAdd(&cursor[d], 1);
        col[p] = src[e];
    }
}

// ---------------- x pre-scale: xs[m] = dinv[m] * x[m]  (64-dim rows) ----------------

__global__ __launch_bounds__(256) void k_xscale(const float* __restrict__ x,
                                                const float* __restrict__ dinv,
                                                float* __restrict__ xs) {
    int i = blockIdx.x * 256 + threadIdx.x;   // exact grid: N_NODES*16
    int m = i >> 4;
    float dm = dinv[m];
    float4 v = ((const float4*)x)[i];
    ((float4*)xs)[i] = make_float4(dm * v.x, dm * v.y, dm * v.z, dm * v.w);
}

// ---------------- gather64: agg[d] = dinv[d] * (xs[d] + sum_{s in N(d)} xs[s]) ----------------
// half-wave (32 lanes) per node, lane c owns float2 chunk c (64 floats = 32 float2)

__global__ __launch_bounds__(256) void k_gather64(const float* __restrict__ xs,
                                                  const int* __restrict__ row_ptr,
                                                  const int* __restrict__ col,
                                                  const float* __restrict__ dinv,
                                                  float* __restrict__ agg) {
    const int g = blockIdx.x * 8 + (threadIdx.x >> 5);   // grid 6250*8 = 50000 exact
    const int c = threadIdx.x & 31;
    const float2* __restrict__ r = (const float2*)xs;

    float2 v = r[(size_t)g * 32 + c];
    float ax = v.x, ay = v.y;

    const int beg = row_ptr[g], end = row_ptr[g + 1];
    int sn = (beg < end) ? col[beg] : 0;
    for (int j = beg; j < end; j++) {
        int s = sn;
        int j1 = (j + 1 < end) ? j + 1 : j;
        sn = col[j1];
        float2 u = r[(size_t)s * 32 + c];
        ax += u.x;
        ay += u.y;
    }
    float dm = dinv[g];
    ((float2*)agg)[(size_t)g * 32 + c] = make_float2(dm * ax, dm * ay);
}

// ---------------- gather128: out[d] = relu(dinv[d] * (ts[d] + sum ts[s]) + b) ----------------

__global__ __launch_bounds__(256) void k_gather128(const float* __restrict__ ts,
                                                   const int* __restrict__ row_ptr,
                                                   const int* __restrict__ col,
                                                   const float* __restrict__ dinv,
                                                   const float* __restrict__ bias,
                                                   float* __restrict__ out) {
    const int g = blockIdx.x * 8 + (threadIdx.x >> 5);   // grid 6250*8 = 50000 exact
    const int c = threadIdx.x & 31;
    const float4* __restrict__ t4 = (const float4*)ts;

    float4 v = t4[(size_t)g * 32 + c];
    float ax = v.x, ay = v.y, az = v.z, aw = v.w;

    const int beg = row_ptr[g], end = row_ptr[g + 1];
    int sn = (beg < end) ? col[beg] : 0;
    for (int j = beg; j < end; j++) {
        int s = sn;
        int j1 = (j + 1 < end) ? j + 1 : j;
        sn = col[j1];
        float4 u = t4[(size_t)s * 32 + c];
        ax += u.x;
        ay += u.y;
        az += u.z;
        aw += u.w;
    }
    float dm = dinv[g];
    float4 b = ((const float4*)bias)[c];
    float4 o;
    o.x = fmaxf(fmaf(dm, ax, b.x), 0.f);
    o.y = fmaxf(fmaf(dm, ay, b.y), 0.f);
    o.z = fmaxf(fmaf(dm, az, b.z), 0.f);
    o.w = fmaxf(fmaf(dm, aw, b.w), 0.f);
    ((float4*)out)[(size_t)g * 32 + c] = o;
}

// ---------------- GEMM: O[m][n] = sum_k X[m][k] * W[n][k], N=128 ----------------
// MODE 1: O = relu(acc + bias[n]);  MODE 2: O = dinv[m] * acc

template<int K, int MODE>
__global__ __launch_bounds__(256) void k_gemm_nt(const float* __restrict__ X,
                                                 const float* __restrict__ W,
                                                 const float* __restrict__ bias,
                                                 const float* __restrict__ dinv,
                                                 float* __restrict__ O) {
    constexpr int KC = 64;
    __shared__ float wsT[KC * 132];
    __shared__ float xsT[KC * 68];
    const int tid = threadIdx.x;
    const int bm = blockIdx.x * 64;
    const int fg = tid & 31;
    const int ng = tid >> 5;

    float acc[8][4];
#pragma unroll
    for (int i = 0; i < 8; i++)
#pragma unroll
        for (int j = 0; j < 4; j++) acc[i][j] = 0.f;

    for (int k0 = 0; k0 < K; k0 += KC) {
        for (int i = tid; i < HID_DIM * KC; i += 256) {
            int n = i >> 6, k = i & 63;
            wsT[k * 132 + n] = W[n * K + k0 + k];
        }
        for (int i = tid; i < 64 * KC; i += 256) {
            int r = i >> 6, k = i & 63;
            int m = bm + r;
            xsT[k * 68 + r] = (m < N_NODES) ? X[(size_t)m * K + k0 + k] : 0.f;
        }
        __syncthreads();
#pragma unroll 4
        for (int k = 0; k < KC; k++) {
            const float4 w4 = *(const float4*)&wsT[k * 132 + 4 * fg];
            const float4 xa = *(const float4*)&xsT[k * 68 + 8 * ng];
            const float4 xb = *(const float4*)&xsT[k * 68 + 8 * ng + 4];
            float xv[8] = {xa.x, xa.y, xa.z, xa.w, xb.x, xb.y, xb.z, xb.w};
            float wv[4] = {w4.x, w4.y, w4.z, w4.w};
#pragma unroll
            for (int i = 0; i < 8; i++)
#pragma unroll
                for (int j = 0; j < 4; j++)
                    acc[i][j] = fmaf(xv[i], wv[j], acc[i][j]);
        }
        __syncthreads();
    }
    float4 bv = make_float4(0.f, 0.f, 0.f, 0.f);
    if (MODE == 1) bv = ((const float4*)bias)[fg];
#pragma unroll
    for (int i = 0; i < 8; i++) {
        int m = bm + 8 * ng + i;
        if (m < N_NODES) {
            float4 o;
            if (MODE == 1) {
                o.x = fmaxf(acc[i][0] + bv.x, 0.f);
                o.y = fmaxf(acc[i][1] + bv.y, 0.f);
                o.z = fmaxf(acc[i][2] + bv.z, 0.f);
                o.w = fmaxf(acc[i][3] + bv.w, 0.f);
            } else {
                float dm = dinv[m];
                o.x = dm * acc[i][0];
                o.y = dm * acc[i][1];
                o.z = dm * acc[i][2];
                o.w = dm * acc[i][3];
            }
            *(float4*)&O[(size_t)m * HID_DIM + 4 * fg] = o;
        }
    }
}

// ---------------- fused mean-pool + FC head ----------------

__global__ __launch_bounds__(256) void k_pool_fc(const float* __restrict__ h,
                                                 const int* __restrict__ gstart,
                                                 const float* __restrict__ fcw,
                                                 const float* __restrict__ fcb,
                                                 float* __restrict__ out) {
    const int g = blockIdx.x;
    const int f = threadIdx.x & 127;
    const int s = threadIdx.x >> 7;        // 0 or 1
    const int beg = gstart[g], end = gstart[g + 1];

    float acc = 0.f;
#pragma unroll 4
    for (int m = beg + s; m < end; m += 2)
        acc += h[(size_t)m * HID_DIM + f];

    __shared__ float tmp[256];
    __shared__ float pool[HID_DIM];
    tmp[threadIdx.x] = acc;
    __syncthreads();
    if (s == 0) {
        float tot = tmp[f] + tmp[128 + f];
        float c = fmaxf((float)(end - beg), 1.f);
        pool[f] = tot / c;
    }
    __syncthreads();
    if (threadIdx.x < OUT_DIM) {
        float a = fcb[threadIdx.x];
#pragma unroll 8
        for (int k = 0; k < HID_DIM; k++)
            a = fmaf(pool[k], fcw[threadIdx.x * HID_DIM + k], a);
        out[g * OUT_DIM + threadIdx.x] = a;
    }
}

// ---------------- launch ----------------

extern "C" void kernel_launch(void* const* d_in, const int* in_sizes, int n_in,
                              void* d_out, int out_size, void* d_ws, size_t ws_size,
                              hipStream_t stream) {
    const float* x   = (const float*)d_in[0];
    const int*  eidx = (const int*)d_in[1];
    const int* batch = (const int*)d_in[2];
    const float* w1  = (const float*)d_in[3];
    const float* b1  = (const float*)d_in[4];
    const float* w2  = (const float*)d_in[5];
    const float* b2  = (const float*)d_in[6];
    const float* fcw = (const float*)d_in[7];
    const float* fcb = (const float*)d_in[8];
    float* out = (float*)d_out;
    const int* src = eidx;             // edge_index[0]
    const int* dst = eidx + N_EDGES;   // edge_index[1]

    char* w = (char*)d_ws;
    float* bufA    = (float*)(w);                 // 25,600,000 B  (ts2; early: xs+agg)
    float* xs      = (float*)(w);                 // 12,800,000 B  (first half of bufA)
    float* agg     = (float*)(w + 12800000);      // 12,800,000 B  (second half of bufA)
    float* bufB    = (float*)(w + 25600000);      // 25,600,000 B  (h1, then out2)
    int*   deg     = (int*)  (w + 51200000);      // 200,000 B
    int*   row_ptr = (int*)  (w + 51400000);      // 200,064 B
    int*   cursor  = (int*)  (w + 51600064);      // 200,000 B
    float* dinv    = (float*)(w + 51800064);      // 200,000 B
    int*   col     = (int*)  (w + 52000064);      // 3,200,000 B
    int*   gstart  = (int*)  (w + 55200064);      // 260 B
    int*   bsum    = (int*)  (w + 55200384);      // 1024 B
    int*   boff    = (int*)  (w + 55201408);      // 1024 B

    dim3 b256(256);

    // CSR build (graph static across both layers) + graph boundaries
    hipMemsetAsync(deg, 0, N_NODES * sizeof(int), stream);
    k_degcount<<<dim3((N_EDGES + 255) / 256), b256, 0, stream>>>(dst, deg);
    k_bounds<<<dim3((N_NODES + 255) / 256), b256, 0, stream>>>(batch, gstart);
    k_scan1<<<dim3(SCAN_BLOCKS), b256, 0, stream>>>(deg, bsum, dinv);
    k_scan2<<<dim3(1), b256, 0, stream>>>(bsum, boff);
    k_scan3<<<dim3(SCAN_BLOCKS), b256, 0, stream>>>(deg, boff, row_ptr, cursor);
    k_fill<<<dim3((N_EDGES + 255) / 256), b256, 0, stream>>>(src, dst, cursor, col);

    // layer 1 (aggregate-then-transform): xs = dinv*x; agg = dinv*(A xs); h1 = relu(agg@W1^T + b1)
    k_xscale<<<dim3(N_NODES * 16 / 256), b256, 0, stream>>>(x, dinv, xs);
    k_gather64<<<dim3(N_NODES / 8), b256, 0, stream>>>(xs, row_ptr, col, dinv, agg);
    k_gemm_nt<IN_DIM, 1><<<dim3((N_NODES + 63) / 64), b256, 0, stream>>>(agg, w1, b1, dinv, bufB);

    // layer 2 (transform-then-aggregate): ts2 = dinv*(h1@W2^T); out2 = relu(dinv*(A ts2) + b2)
    k_gemm_nt<HID_DIM, 2><<<dim3((N_NODES + 63) / 64), b256, 0, stream>>>(bufB, w2, b1, dinv, bufA);
    k_gather128<<<dim3(N_NODES / 8), b256, 0, stream>>>(bufA, row_ptr, col, dinv, b2, bufB);

    // fused mean-pool + FC head
    k_pool_fc<<<dim3(N_GRAPHS), b256, 0, stream>>>(bufB, gstart, fcw, fcb, out);
}

// Round 6
// 363.948 us; speedup vs baseline: 8.9964x; 1.0787x over previous
//
#include <hip/hip_runtime.h>

#define N_NODES 50000
#define N_EDGES 800000
#define IN_DIM 64
#define HID_DIM 128
#define OUT_DIM 10
#define N_GRAPHS 64

#define SCAN_BLOCKS ((N_NODES + 255) / 256)   // 196

// ---------------- degree ----------------

__global__ void k_degcount(const int* __restrict__ dst, int* __restrict__ deg) {
    int e = blockIdx.x * blockDim.x + threadIdx.x;
    if (e < N_EDGES) atomicAdd(&deg[dst[e]], 1);
}

// ---------------- 3-phase parallel scan of deg -> row_ptr (+bounds fused) ----------------

// phase 1: per-block sum of deg -> bsum; dinv = rsqrt(deg+1); graph bounds from sorted batch
__global__ __launch_bounds__(256) void k_scan1(const int* __restrict__ deg,
                                               int* __restrict__ bsum,
                                               float* __restrict__ dinv,
                                               const int* __restrict__ batch,
                                               int* __restrict__ gstart) {
    __shared__ int red[256];
    int i = blockIdx.x * 256 + threadIdx.x;
    int d = (i < N_NODES) ? deg[i] : 0;
    if (i < N_NODES) {
        dinv[i] = rsqrtf((float)(d + 1));
        // graph boundaries (batch sorted)
        int b = batch[i];
        if (i == 0) {
            for (int g = 0; g <= b; g++) gstart[g] = 0;
        } else {
            int a = batch[i - 1];
            for (int g = a + 1; g <= b; g++) gstart[g] = i;
        }
        if (i == N_NODES - 1) {
            for (int g = b + 1; g <= N_GRAPHS; g++) gstart[g] = N_NODES;
        }
    }
    red[threadIdx.x] = d;
    __syncthreads();
#pragma unroll
    for (int off = 128; off > 0; off >>= 1) {
        if (threadIdx.x < off) red[threadIdx.x] += red[threadIdx.x + off];
        __syncthreads();
    }
    if (threadIdx.x == 0) bsum[blockIdx.x] = red[0];
}

__global__ __launch_bounds__(256) void k_scan2(const int* __restrict__ bsum,
                                               int* __restrict__ boff) {
    __shared__ int s[256];
    int t = threadIdx.x;
    s[t] = (t < SCAN_BLOCKS) ? bsum[t] : 0;
    __syncthreads();
#pragma unroll
    for (int off = 1; off < 256; off <<= 1) {
        int v = (t >= off) ? s[t - off] : 0;
        __syncthreads();
        s[t] += v;
        __syncthreads();
    }
    if (t < SCAN_BLOCKS) boff[t] = (t > 0) ? s[t - 1] : 0;
}

__global__ __launch_bounds__(256) void k_scan3(const int* __restrict__ deg,
                                               const int* __restrict__ boff,
                                               int* __restrict__ row_ptr,
                                               int* __restrict__ cursor) {
    __shared__ int s[256];
    int t = threadIdx.x;
    int i = blockIdx.x * 256 + t;
    int d = (i < N_NODES) ? deg[i] : 0;
    s[t] = d;
    __syncthreads();
#pragma unroll
    for (int off = 1; off < 256; off <<= 1) {
        int v = (t >= off) ? s[t - off] : 0;
        __syncthreads();
        s[t] += v;
        __syncthreads();
    }
    if (i < N_NODES) {
        int excl = boff[blockIdx.x] + s[t] - d;
        row_ptr[i] = excl;
        cursor[i] = excl;
    }
    if (i == 0) row_ptr[N_NODES] = N_EDGES;
}

__global__ void k_fill(const int* __restrict__ src, const int* __restrict__ dst,
                       int* __restrict__ cursor, int* __restrict__ col) {
    int e = blockIdx.x * blockDim.x + threadIdx.x;
    if (e < N_EDGES) {
        int d = dst[e];
        int p = atomicAdd(&cursor[d], 1);
        col[p] = src[e];
    }
}

// ---------------- x pre-scale: xs[m] = dinv[m] * x[m]  (64-dim rows) ----------------

__global__ __launch_bounds__(256) void k_xscale(const float* __restrict__ x,
                                                const float* __restrict__ dinv,
                                                float* __restrict__ xs) {
    int i = blockIdx.x * 256 + threadIdx.x;   // exact grid: N_NODES*16
    int m = i >> 4;
    float dm = dinv[m];
    float4 v = ((const float4*)x)[i];
    ((float4*)xs)[i] = make_float4(dm * v.x, dm * v.y, dm * v.z, dm * v.w);
}

// ---------------- gather64: agg[d] = dinv[d] * (xs[d] + sum_{s in N(d)} xs[s]) ----------------
// 32 lanes per node, lane c owns float2 chunk c; edge loop batched x8 for MLP.

__global__ __launch_bounds__(256) void k_gather64(const float* __restrict__ xs,
                                                  const int* __restrict__ row_ptr,
                                                  const int* __restrict__ col,
                                                  const float* __restrict__ dinv,
                                                  float* __restrict__ agg) {
    const int g = blockIdx.x * 8 + (threadIdx.x >> 5);   // grid 6250*8 = 50000 exact
    const int c = threadIdx.x & 31;
    const float2* __restrict__ r = (const float2*)xs;

    float2 v = r[(size_t)g * 32 + c];
    float ax = v.x, ay = v.y;

    const int beg = row_ptr[g], end = row_ptr[g + 1];
    for (int j = beg; j < end; j += 8) {
        int   idx[8];
        float wt[8];
#pragma unroll
        for (int k = 0; k < 8; k++) {
            int jj = j + k;
            bool in = jj < end;
            idx[k] = in ? jj : (end - 1);
            wt[k] = in ? 1.f : 0.f;
        }
        int s[8];
#pragma unroll
        for (int k = 0; k < 8; k++) s[k] = col[idx[k]];
        float2 u[8];
#pragma unroll
        for (int k = 0; k < 8; k++) u[k] = r[(size_t)s[k] * 32 + c];
#pragma unroll
        for (int k = 0; k < 8; k++) {
            ax = fmaf(wt[k], u[k].x, ax);
            ay = fmaf(wt[k], u[k].y, ay);
        }
    }
    float dm = dinv[g];
    ((float2*)agg)[(size_t)g * 32 + c] = make_float2(dm * ax, dm * ay);
}

// ---------------- gather128: out[d] = relu(dinv[d] * (ts[d] + sum ts[s]) + b) ----------------
// 32 lanes per node, lane c owns float4 chunk c; edge loop batched x4 for MLP.

__global__ __launch_bounds__(256) void k_gather128(const float* __restrict__ ts,
                                                   const int* __restrict__ row_ptr,
                                                   const int* __restrict__ col,
                                                   const float* __restrict__ dinv,
                                                   const float* __restrict__ bias,
                                                   float* __restrict__ out) {
    const int g = blockIdx.x * 8 + (threadIdx.x >> 5);   // grid 6250*8 = 50000 exact
    const int c = threadIdx.x & 31;
    const float4* __restrict__ t4 = (const float4*)ts;

    float4 v = t4[(size_t)g * 32 + c];
    float ax = v.x, ay = v.y, az = v.z, aw = v.w;

    const int beg = row_ptr[g], end = row_ptr[g + 1];
    for (int j = beg; j < end; j += 4) {
        int   idx[4];
        float wt[4];
#pragma unroll
        for (int k = 0; k < 4; k++) {
            int jj = j + k;
            bool in = jj < end;
            idx[k] = in ? jj : (end - 1);
            wt[k] = in ? 1.f : 0.f;
        }
        int s[4];
#pragma unroll
        for (int k = 0; k < 4; k++) s[k] = col[idx[k]];
        float4 u[4];
#pragma unroll
        for (int k = 0; k < 4; k++) u[k] = t4[(size_t)s[k] * 32 + c];
#pragma unroll
        for (int k = 0; k < 4; k++) {
            ax = fmaf(wt[k], u[k].x, ax);
            ay = fmaf(wt[k], u[k].y, ay);
            az = fmaf(wt[k], u[k].z, az);
            aw = fmaf(wt[k], u[k].w, aw);
        }
    }
    float dm = dinv[g];
    float4 b = ((const float4*)bias)[c];
    float4 o;
    o.x = fmaxf(fmaf(dm, ax, b.x), 0.f);
    o.y = fmaxf(fmaf(dm, ay, b.y), 0.f);
    o.z = fmaxf(fmaf(dm, az, b.z), 0.f);
    o.w = fmaxf(fmaf(dm, aw, b.w), 0.f);
    ((float4*)out)[(size_t)g * 32 + c] = o;
}

// ---------------- GEMM: O[m][n] = sum_k X[m][k] * W[n][k], N=128 ----------------
// MODE 1: O = relu(acc + bias[n]);  MODE 2: O = dinv[m] * acc

template<int K, int MODE>
__global__ __launch_bounds__(256) void k_gemm_nt(const float* __restrict__ X,
                                                 const float* __restrict__ W,
                                                 const float* __restrict__ bias,
                                                 const float* __restrict__ dinv,
                                                 float* __restrict__ O) {
    constexpr int KC = 64;
    __shared__ float wsT[KC * 132];
    __shared__ float xsT[KC * 68];
    const int tid = threadIdx.x;
    const int bm = blockIdx.x * 64;
    const int fg = tid & 31;
    const int ng = tid >> 5;

    float acc[8][4];
#pragma unroll
    for (int i = 0; i < 8; i++)
#pragma unroll
        for (int j = 0; j < 4; j++) acc[i][j] = 0.f;

    for (int k0 = 0; k0 < K; k0 += KC) {
        for (int i = tid; i < HID_DIM * KC; i += 256) {
            int n = i >> 6, k = i & 63;
            wsT[k * 132 + n] = W[n * K + k0 + k];
        }
        for (int i = tid; i < 64 * KC; i += 256) {
            int r = i >> 6, k = i & 63;
            int m = bm + r;
            xsT[k * 68 + r] = (m < N_NODES) ? X[(size_t)m * K + k0 + k] : 0.f;
        }
        __syncthreads();
#pragma unroll 4
        for (int k = 0; k < KC; k++) {
            const float4 w4 = *(const float4*)&wsT[k * 132 + 4 * fg];
            const float4 xa = *(const float4*)&xsT[k * 68 + 8 * ng];
            const float4 xb = *(const float4*)&xsT[k * 68 + 8 * ng + 4];
            float xv[8] = {xa.x, xa.y, xa.z, xa.w, xb.x, xb.y, xb.z, xb.w};
            float wv[4] = {w4.x, w4.y, w4.z, w4.w};
#pragma unroll
            for (int i = 0; i < 8; i++)
#pragma unroll
                for (int j = 0; j < 4; j++)
                    acc[i][j] = fmaf(xv[i], wv[j], acc[i][j]);
        }
        __syncthreads();
    }
    float4 bv = make_float4(0.f, 0.f, 0.f, 0.f);
    if (MODE == 1) bv = ((const float4*)bias)[fg];
#pragma unroll
    for (int i = 0; i < 8; i++) {
        int m = bm + 8 * ng + i;
        if (m < N_NODES) {
            float4 o;
            if (MODE == 1) {
                o.x = fmaxf(acc[i][0] + bv.x, 0.f);
                o.y = fmaxf(acc[i][1] + bv.y, 0.f);
                o.z = fmaxf(acc[i][2] + bv.z, 0.f);
                o.w = fmaxf(acc[i][3] + bv.w, 0.f);
            } else {
                float dm = dinv[m];
                o.x = dm * acc[i][0];
                o.y = dm * acc[i][1];
                o.z = dm * acc[i][2];
                o.w = dm * acc[i][3];
            }
            *(float4*)&O[(size_t)m * HID_DIM + 4 * fg] = o;
        }
    }
}

// ---------------- fused mean-pool + FC head ----------------

__global__ __launch_bounds__(256) void k_pool_fc(const float* __restrict__ h,
                                                 const int* __restrict__ gstart,
                                                 const float* __restrict__ fcw,
                                                 const float* __restrict__ fcb,
                                                 float* __restrict__ out) {
    const int g = blockIdx.x;
    const int f = threadIdx.x & 127;
    const int s = threadIdx.x >> 7;        // 0 or 1
    const int beg = gstart[g], end = gstart[g + 1];

    float acc = 0.f;
#pragma unroll 4
    for (int m = beg + s; m < end; m += 2)
        acc += h[(size_t)m * HID_DIM + f];

    __shared__ float tmp[256];
    __shared__ float pool[HID_DIM];
    tmp[threadIdx.x] = acc;
    __syncthreads();
    if (s == 0) {
        float tot = tmp[f] + tmp[128 + f];
        float c = fmaxf((float)(end - beg), 1.f);
        pool[f] = tot / c;
    }
    __syncthreads();
    if (threadIdx.x < OUT_DIM) {
        float a = fcb[threadIdx.x];
#pragma unroll 8
        for (int k = 0; k < HID_DIM; k++)
            a = fmaf(pool[k], fcw[threadIdx.x * HID_DIM + k], a);
        out[g * OUT_DIM + threadIdx.x] = a;
    }
}

// ---------------- launch ----------------

extern "C" void kernel_launch(void* const* d_in, const int* in_sizes, int n_in,
                              void* d_out, int out_size, void* d_ws, size_t ws_size,
                              hipStream_t stream) {
    const float* x   = (const float*)d_in[0];
    const int*  eidx = (const int*)d_in[1];
    const int* batch = (const int*)d_in[2];
    const float* w1  = (const float*)d_in[3];
    const float* b1  = (const float*)d_in[4];
    const float* w2  = (const float*)d_in[5];
    const float* b2  = (const float*)d_in[6];
    const float* fcw = (const float*)d_in[7];
    const float* fcb = (const float*)d_in[8];
    float* out = (float*)d_out;
    const int* src = eidx;             // edge_index[0]
    const int* dst = eidx + N_EDGES;   // edge_index[1]

    char* w = (char*)d_ws;
    float* bufA    = (float*)(w);                 // 25,600,000 B  (ts2; early: xs+agg)
    float* xs      = (float*)(w);                 // 12,800,000 B
    float* agg     = (float*)(w + 12800000);      // 12,800,000 B
    float* bufB    = (float*)(w + 25600000);      // 25,600,000 B  (h1, then out2)
    int*   deg     = (int*)  (w + 51200000);      // 200,000 B
    int*   row_ptr = (int*)  (w + 51400000);      // 200,064 B
    int*   cursor  = (int*)  (w + 51600064);      // 200,000 B
    float* dinv    = (float*)(w + 51800064);      // 200,000 B
    int*   col     = (int*)  (w + 52000064);      // 3,200,000 B
    int*   gstart  = (int*)  (w + 55200064);      // 260 B
    int*   bsum    = (int*)  (w + 55200384);      // 1024 B
    int*   boff    = (int*)  (w + 55201408);      // 1024 B

    dim3 b256(256);

    // CSR build (graph static across both layers) + graph boundaries
    hipMemsetAsync(deg, 0, N_NODES * sizeof(int), stream);
    k_degcount<<<dim3((N_EDGES + 255) / 256), b256, 0, stream>>>(dst, deg);
    k_scan1<<<dim3(SCAN_BLOCKS), b256, 0, stream>>>(deg, bsum, dinv, batch, gstart);
    k_scan2<<<dim3(1), b256, 0, stream>>>(bsum, boff);
    k_scan3<<<dim3(SCAN_BLOCKS), b256, 0, stream>>>(deg, boff, row_ptr, cursor);
    k_fill<<<dim3((N_EDGES + 255) / 256), b256, 0, stream>>>(src, dst, cursor, col);

    // layer 1 (aggregate-then-transform): xs = dinv*x; agg = dinv*(A xs); h1 = relu(agg@W1^T + b1)
    k_xscale<<<dim3(N_NODES * 16 / 256), b256, 0, stream>>>(x, dinv, xs);
    k_gather64<<<dim3(N_NODES / 8), b256, 0, stream>>>(xs, row_ptr, col, dinv, agg);
    k_gemm_nt<IN_DIM, 1><<<dim3((N_NODES + 63) / 64), b256, 0, stream>>>(agg, w1, b1, dinv, bufB);

    // layer 2 (transform-then-aggregate): ts2 = dinv*(h1@W2^T); out2 = relu(dinv*(A ts2) + b2)
    k_gemm_nt<HID_DIM, 2><<<dim3((N_NODES + 63) / 64), b256, 0, stream>>>(bufB, w2, b1, dinv, bufA);
    k_gather128<<<dim3(N_NODES / 8), b256, 0, stream>>>(bufA, row_ptr, col, dinv, b2, bufB);

    // fused mean-pool + FC head
    k_pool_fc<<<dim3(N_GRAPHS), b256, 0, stream>>>(bufB, gstart, fcw, fcb, out);
}

// Round 7
// 324.015 us; speedup vs baseline: 10.1051x; 1.1232x over previous
//
#include <hip/hip_runtime.h>

#define N_NODES 50000
#define N_EDGES 800000
#define IN_DIM 64
#define HID_DIM 128
#define OUT_DIM 10
#define N_GRAPHS 64

#define SCAN_BLOCKS ((N_NODES + 255) / 256)   // 196

// ---- bf16 pack/unpack helpers (RNE pack; unpack = shift/mask) ----
__device__ __forceinline__ unsigned bf16pack2(float a, float b) {
    unsigned ua = __float_as_uint(a), ub = __float_as_uint(b);
    ua = (ua + 0x7FFFu + ((ua >> 16) & 1u)) >> 16;
    ub = (ub + 0x7FFFu + ((ub >> 16) & 1u)) >> 16;
    return ua | (ub << 16);
}
__device__ __forceinline__ float bf16lo(unsigned u) { return __uint_as_float(u << 16); }
__device__ __forceinline__ float bf16hi(unsigned u) { return __uint_as_float(u & 0xFFFF0000u); }

// ---------------- degree ----------------

__global__ void k_degcount(const int* __restrict__ dst, int* __restrict__ deg) {
    int e = blockIdx.x * blockDim.x + threadIdx.x;
    if (e < N_EDGES) atomicAdd(&deg[dst[e]], 1);
}

// ---------------- 3-phase parallel scan of deg -> row_ptr (+bounds fused) ----------------

__global__ __launch_bounds__(256) void k_scan1(const int* __restrict__ deg,
                                               int* __restrict__ bsum,
                                               float* __restrict__ dinv,
                                               const int* __restrict__ batch,
                                               int* __restrict__ gstart) {
    __shared__ int red[256];
    int i = blockIdx.x * 256 + threadIdx.x;
    int d = (i < N_NODES) ? deg[i] : 0;
    if (i < N_NODES) {
        dinv[i] = rsqrtf((float)(d + 1));
        int b = batch[i];
        if (i == 0) {
            for (int g = 0; g <= b; g++) gstart[g] = 0;
        } else {
            int a = batch[i - 1];
            for (int g = a + 1; g <= b; g++) gstart[g] = i;
        }
        if (i == N_NODES - 1) {
            for (int g = b + 1; g <= N_GRAPHS; g++) gstart[g] = N_NODES;
        }
    }
    red[threadIdx.x] = d;
    __syncthreads();
#pragma unroll
    for (int off = 128; off > 0; off >>= 1) {
        if (threadIdx.x < off) red[threadIdx.x] += red[threadIdx.x + off];
        __syncthreads();
    }
    if (threadIdx.x == 0) bsum[blockIdx.x] = red[0];
}

__global__ __launch_bounds__(256) void k_scan2(const int* __restrict__ bsum,
                                               int* __restrict__ boff) {
    __shared__ int s[256];
    int t = threadIdx.x;
    s[t] = (t < SCAN_BLOCKS) ? bsum[t] : 0;
    __syncthreads();
#pragma unroll
    for (int off = 1; off < 256; off <<= 1) {
        int v = (t >= off) ? s[t - off] : 0;
        __syncthreads();
        s[t] += v;
        __syncthreads();
    }
    if (t < SCAN_BLOCKS) boff[t] = (t > 0) ? s[t - 1] : 0;
}

__global__ __launch_bounds__(256) void k_scan3(const int* __restrict__ deg,
                                               const int* __restrict__ boff,
                                               int* __restrict__ row_ptr,
                                               int* __restrict__ cursor) {
    __shared__ int s[256];
    int t = threadIdx.x;
    int i = blockIdx.x * 256 + t;
    int d = (i < N_NODES) ? deg[i] : 0;
    s[t] = d;
    __syncthreads();
#pragma unroll
    for (int off = 1; off < 256; off <<= 1) {
        int v = (t >= off) ? s[t - off] : 0;
        __syncthreads();
        s[t] += v;
        __syncthreads();
    }
    if (i < N_NODES) {
        int excl = boff[blockIdx.x] + s[t] - d;
        row_ptr[i] = excl;
        cursor[i] = excl;
    }
    if (i == 0) row_ptr[N_NODES] = N_EDGES;
}

__global__ void k_fill(const int* __restrict__ src, const int* __restrict__ dst,
                       int* __restrict__ cursor, int* __restrict__ col) {
    int e = blockIdx.x * blockDim.x + threadIdx.x;
    if (e < N_EDGES) {
        int d = dst[e];
        int p = atomicAdd(&cursor[d], 1);
        col[p] = src[e];
    }
}

// ---------------- x pre-scale + bf16 pack: xs[m] = bf16(dinv[m] * x[m]) ----------------
// 64-dim rows -> 32 uints per row; thread i handles 2 floats -> 1 uint

__global__ __launch_bounds__(256) void k_xscale(const float* __restrict__ x,
                                                const float* __restrict__ dinv,
                                                unsigned* __restrict__ xs) {
    int i = blockIdx.x * 256 + threadIdx.x;   // exact grid: N_NODES*32
    int m = i >> 5;
    float dm = dinv[m];
    float2 v = ((const float2*)x)[i];
    xs[i] = bf16pack2(dm * v.x, dm * v.y);
}

// ---------------- gather64 (bf16 rows): agg[d] = dinv[d]*(xs[d] + sum xs[s]) ----------------
// 32 lanes per node, lane c owns uint chunk c (2 bf16); edge loop batched x8.

__global__ __launch_bounds__(256) void k_gather64(const unsigned* __restrict__ xs,
                                                  const int* __restrict__ row_ptr,
                                                  const int* __restrict__ col,
                                                  const float* __restrict__ dinv,
                                                  float* __restrict__ agg) {
    const int g = blockIdx.x * 8 + (threadIdx.x >> 5);   // grid 6250*8 = 50000 exact
    const int c = threadIdx.x & 31;

    unsigned v = xs[(size_t)g * 32 + c];
    float ax = bf16lo(v), ay = bf16hi(v);

    const int beg = row_ptr[g], end = row_ptr[g + 1];
    for (int j = beg; j < end; j += 8) {
        int   idx[8];
        float wt[8];
#pragma unroll
        for (int k = 0; k < 8; k++) {
            int jj = j + k;
            bool in = jj < end;
            idx[k] = in ? jj : (end - 1);
            wt[k] = in ? 1.f : 0.f;
        }
        int s[8];
#pragma unroll
        for (int k = 0; k < 8; k++) s[k] = col[idx[k]];
        unsigned u[8];
#pragma unroll
        for (int k = 0; k < 8; k++) u[k] = xs[(size_t)s[k] * 32 + c];
#pragma unroll
        for (int k = 0; k < 8; k++) {
            ax = fmaf(wt[k], bf16lo(u[k]), ax);
            ay = fmaf(wt[k], bf16hi(u[k]), ay);
        }
    }
    float dm = dinv[g];
    ((float2*)agg)[(size_t)g * 32 + c] = make_float2(dm * ax, dm * ay);
}

// ---------------- gather128 (bf16 rows): out[d] = relu(dinv[d]*(ts[d]+sum ts[s]) + b) ----------------
// 32 lanes per node, lane c owns uint2 chunk c (4 bf16); edge loop batched x8.

__global__ __launch_bounds__(256) void k_gather128(const uint2* __restrict__ ts,
                                                   const int* __restrict__ row_ptr,
                                                   const int* __restrict__ col,
                                                   const float* __restrict__ dinv,
                                                   const float* __restrict__ bias,
                                                   float* __restrict__ out) {
    const int g = blockIdx.x * 8 + (threadIdx.x >> 5);   // grid 6250*8 = 50000 exact
    const int c = threadIdx.x & 31;

    uint2 v = ts[(size_t)g * 32 + c];
    float ax = bf16lo(v.x), ay = bf16hi(v.x), az = bf16lo(v.y), aw = bf16hi(v.y);

    const int beg = row_ptr[g], end = row_ptr[g + 1];
    for (int j = beg; j < end; j += 8) {
        int   idx[8];
        float wt[8];
#pragma unroll
        for (int k = 0; k < 8; k++) {
            int jj = j + k;
            bool in = jj < end;
            idx[k] = in ? jj : (end - 1);
            wt[k] = in ? 1.f : 0.f;
        }
        int s[8];
#pragma unroll
        for (int k = 0; k < 8; k++) s[k] = col[idx[k]];
        uint2 u[8];
#pragma unroll
        for (int k = 0; k < 8; k++) u[k] = ts[(size_t)s[k] * 32 + c];
#pragma unroll
        for (int k = 0; k < 8; k++) {
            ax = fmaf(wt[k], bf16lo(u[k].x), ax);
            ay = fmaf(wt[k], bf16hi(u[k].x), ay);
            az = fmaf(wt[k], bf16lo(u[k].y), az);
            aw = fmaf(wt[k], bf16hi(u[k].y), aw);
        }
    }
    float dm = dinv[g];
    float4 b = ((const float4*)bias)[c];
    float4 o;
    o.x = fmaxf(fmaf(dm, ax, b.x), 0.f);
    o.y = fmaxf(fmaf(dm, ay, b.y), 0.f);
    o.z = fmaxf(fmaf(dm, az, b.z), 0.f);
    o.w = fmaxf(fmaf(dm, aw, b.w), 0.f);
    ((float4*)out)[(size_t)g * 32 + c] = o;
}

// ---------------- GEMM: O[m][n] = sum_k X[m][k] * W[n][k], N=128 ----------------
// MODE 1: O(fp32) = relu(acc + bias[n]);  MODE 2: O(bf16-packed) = dinv[m] * acc

template<int K, int MODE>
__global__ __launch_bounds__(256) void k_gemm_nt(const float* __restrict__ X,
                                                 const float* __restrict__ W,
                                                 const float* __restrict__ bias,
                                                 const float* __restrict__ dinv,
                                                 float* __restrict__ O,
                                                 uint2* __restrict__ Ob) {
    constexpr int KC = 64;
    __shared__ float wsT[KC * 132];
    __shared__ float xsT[KC * 68];
    const int tid = threadIdx.x;
    const int bm = blockIdx.x * 64;
    const int fg = tid & 31;
    const int ng = tid >> 5;

    float acc[8][4];
#pragma unroll
    for (int i = 0; i < 8; i++)
#pragma unroll
        for (int j = 0; j < 4; j++) acc[i][j] = 0.f;

    for (int k0 = 0; k0 < K; k0 += KC) {
        for (int i = tid; i < HID_DIM * KC; i += 256) {
            int n = i >> 6, k = i & 63;
            wsT[k * 132 + n] = W[n * K + k0 + k];
        }
        for (int i = tid; i < 64 * KC; i += 256) {
            int r = i >> 6, k = i & 63;
            int m = bm + r;
            xsT[k * 68 + r] = (m < N_NODES) ? X[(size_t)m * K + k0 + k] : 0.f;
        }
        __syncthreads();
#pragma unroll 4
        for (int k = 0; k < KC; k++) {
            const float4 w4 = *(const float4*)&wsT[k * 132 + 4 * fg];
            const float4 xa = *(const float4*)&xsT[k * 68 + 8 * ng];
            const float4 xb = *(const float4*)&xsT[k * 68 + 8 * ng + 4];
            float xv[8] = {xa.x, xa.y, xa.z, xa.w, xb.x, xb.y, xb.z, xb.w};
            float wv[4] = {w4.x, w4.y, w4.z, w4.w};
#pragma unroll
            for (int i = 0; i < 8; i++)
#pragma unroll
                for (int j = 0; j < 4; j++)
                    acc[i][j] = fmaf(xv[i], wv[j], acc[i][j]);
        }
        __syncthreads();
    }
    float4 bv = make_float4(0.f, 0.f, 0.f, 0.f);
    if (MODE == 1) bv = ((const float4*)bias)[fg];
#pragma unroll
    for (int i = 0; i < 8; i++) {
        int m = bm + 8 * ng + i;
        if (m < N_NODES) {
            if (MODE == 1) {
                float4 o;
                o.x = fmaxf(acc[i][0] + bv.x, 0.f);
                o.y = fmaxf(acc[i][1] + bv.y, 0.f);
                o.z = fmaxf(acc[i][2] + bv.z, 0.f);
                o.w = fmaxf(acc[i][3] + bv.w, 0.f);
                *(float4*)&O[(size_t)m * HID_DIM + 4 * fg] = o;
            } else {
                float dm = dinv[m];
                uint2 p;
                p.x = bf16pack2(dm * acc[i][0], dm * acc[i][1]);
                p.y = bf16pack2(dm * acc[i][2], dm * acc[i][3]);
                Ob[(size_t)m * 32 + fg] = p;
            }
        }
    }
}

// ---------------- fused mean-pool + FC head ----------------

__global__ __launch_bounds__(256) void k_pool_fc(const float* __restrict__ h,
                                                 const int* __restrict__ gstart,
                                                 const float* __restrict__ fcw,
                                                 const float* __restrict__ fcb,
                                                 float* __restrict__ out) {
    const int g = blockIdx.x;
    const int f = threadIdx.x & 127;
    const int s = threadIdx.x >> 7;        // 0 or 1
    const int beg = gstart[g], end = gstart[g + 1];

    float acc = 0.f;
#pragma unroll 4
    for (int m = beg + s; m < end; m += 2)
        acc += h[(size_t)m * HID_DIM + f];

    __shared__ float tmp[256];
    __shared__ float pool[HID_DIM];
    tmp[threadIdx.x] = acc;
    __syncthreads();
    if (s == 0) {
        float tot = tmp[f] + tmp[128 + f];
        float c = fmaxf((float)(end - beg), 1.f);
        pool[f] = tot / c;
    }
    __syncthreads();
    if (threadIdx.x < OUT_DIM) {
        float a = fcb[threadIdx.x];
#pragma unroll 8
        for (int k = 0; k < HID_DIM; k++)
            a = fmaf(pool[k], fcw[threadIdx.x * HID_DIM + k], a);
        out[g * OUT_DIM + threadIdx.x] = a;
    }
}

// ---------------- launch ----------------

extern "C" void kernel_launch(void* const* d_in, const int* in_sizes, int n_in,
                              void* d_out, int out_size, void* d_ws, size_t ws_size,
                              hipStream_t stream) {
    const float* x   = (const float*)d_in[0];
    const int*  eidx = (const int*)d_in[1];
    const int* batch = (const int*)d_in[2];
    const float* w1  = (const float*)d_in[3];
    const float* b1  = (const float*)d_in[4];
    const float* w2  = (const float*)d_in[5];
    const float* b2  = (const float*)d_in[6];
    const float* fcw = (const float*)d_in[7];
    const float* fcb = (const float*)d_in[8];
    float* out = (float*)d_out;
    const int* src = eidx;             // edge_index[0]
    const int* dst = eidx + N_EDGES;   // edge_index[1]

    char* w = (char*)d_ws;
    // region A (0..25.6M): layer1: xs(bf16 6.4M) + agg(fp32 12.8M); layer2: ts2(bf16 12.8M)
    unsigned* xs  = (unsigned*)(w);               // 6,400,000 B
    float*    agg = (float*)(w + 6400000);        // 12,800,000 B
    uint2*    ts2 = (uint2*)(w);                  // 12,800,000 B (reuses region A after GEMM1)
    float* bufB    = (float*)(w + 25600000);      // 25,600,000 B (h1, then out2)
    int*   deg     = (int*)  (w + 51200000);      // 200,000 B
    int*   row_ptr = (int*)  (w + 51400000);      // 200,064 B
    int*   cursor  = (int*)  (w + 51600064);      // 200,000 B
    float* dinv    = (float*)(w + 51800064);      // 200,000 B
    int*   col     = (int*)  (w + 52000064);      // 3,200,000 B
    int*   gstart  = (int*)  (w + 55200064);      // 260 B
    int*   bsum    = (int*)  (w + 55200384);      // 1024 B
    int*   boff    = (int*)  (w + 55201408);      // 1024 B

    dim3 b256(256);

    // CSR build (graph static across both layers) + graph boundaries
    hipMemsetAsync(deg, 0, N_NODES * sizeof(int), stream);
    k_degcount<<<dim3((N_EDGES + 255) / 256), b256, 0, stream>>>(dst, deg);
    k_scan1<<<dim3(SCAN_BLOCKS), b256, 0, stream>>>(deg, bsum, dinv, batch, gstart);
    k_scan2<<<dim3(1), b256, 0, stream>>>(bsum, boff);
    k_scan3<<<dim3(SCAN_BLOCKS), b256, 0, stream>>>(deg, boff, row_ptr, cursor);
    k_fill<<<dim3((N_EDGES + 255) / 256), b256, 0, stream>>>(src, dst, cursor, col);

    // layer 1 (aggregate-then-transform, bf16 gather payload):
    k_xscale<<<dim3(N_NODES * 32 / 256), b256, 0, stream>>>(x, dinv, xs);
    k_gather64<<<dim3(N_NODES / 8), b256, 0, stream>>>(xs, row_ptr, col, dinv, agg);
    k_gemm_nt<IN_DIM, 1><<<dim3((N_NODES + 63) / 64), b256, 0, stream>>>(agg, w1, b1, dinv, bufB, (uint2*)0);

    // layer 2 (transform-then-aggregate, bf16 gather payload):
    k_gemm_nt<HID_DIM, 2><<<dim3((N_NODES + 63) / 64), b256, 0, stream>>>(bufB, w2, b1, dinv, (float*)0, ts2);
    k_gather128<<<dim3(N_NODES / 8), b256, 0, stream>>>(ts2, row_ptr, col, dinv, b2, bufB);

    // fused mean-pool + FC head
    k_pool_fc<<<dim3(N_GRAPHS), b256, 0, stream>>>(bufB, gstart, fcw, fcb, out);
}

// Round 8
// 298.130 us; speedup vs baseline: 10.9825x; 1.0868x over previous
//
#include <hip/hip_runtime.h>

#define N_NODES 50000
#define N_EDGES 800000
#define IN_DIM 64
#define HID_DIM 128
#define OUT_DIM 10
#define N_GRAPHS 64

#define SCAN_BLOCKS ((N_NODES + 255) / 256)   // 196

typedef short bf16x8 __attribute__((ext_vector_type(8)));
typedef float f32x4  __attribute__((ext_vector_type(4)));

// ---- bf16 pack/unpack helpers (RNE pack; unpack = shift/mask) ----
__device__ __forceinline__ unsigned bf16pack2(float a, float b) {
    unsigned ua = __float_as_uint(a), ub = __float_as_uint(b);
    ua = (ua + 0x7FFFu + ((ua >> 16) & 1u)) >> 16;
    ub = (ub + 0x7FFFu + ((ub >> 16) & 1u)) >> 16;
    return ua | (ub << 16);
}
__device__ __forceinline__ unsigned short bf16r(float v) {
    unsigned u = __float_as_uint(v);
    u = (u + 0x7FFFu + ((u >> 16) & 1u)) >> 16;
    return (unsigned short)u;
}
__device__ __forceinline__ float bf16lo(unsigned u) { return __uint_as_float(u << 16); }
__device__ __forceinline__ float bf16hi(unsigned u) { return __uint_as_float(u & 0xFFFF0000u); }

// ---------------- degree ----------------

__global__ void k_degcount(const int* __restrict__ dst, int* __restrict__ deg) {
    int e = blockIdx.x * blockDim.x + threadIdx.x;
    if (e < N_EDGES) atomicAdd(&deg[dst[e]], 1);
}

// ---------------- 3-phase parallel scan of deg -> row_ptr (+bounds fused) ----------------

__global__ __launch_bounds__(256) void k_scan1(const int* __restrict__ deg,
                                               int* __restrict__ bsum,
                                               float* __restrict__ dinv,
                                               const int* __restrict__ batch,
                                               int* __restrict__ gstart) {
    __shared__ int red[256];
    int i = blockIdx.x * 256 + threadIdx.x;
    int d = (i < N_NODES) ? deg[i] : 0;
    if (i < N_NODES) {
        dinv[i] = rsqrtf((float)(d + 1));
        int b = batch[i];
        if (i == 0) {
            for (int g = 0; g <= b; g++) gstart[g] = 0;
        } else {
            int a = batch[i - 1];
            for (int g = a + 1; g <= b; g++) gstart[g] = i;
        }
        if (i == N_NODES - 1) {
            for (int g = b + 1; g <= N_GRAPHS; g++) gstart[g] = N_NODES;
        }
    }
    red[threadIdx.x] = d;
    __syncthreads();
#pragma unroll
    for (int off = 128; off > 0; off >>= 1) {
        if (threadIdx.x < off) red[threadIdx.x] += red[threadIdx.x + off];
        __syncthreads();
    }
    if (threadIdx.x == 0) bsum[blockIdx.x] = red[0];
}

__global__ __launch_bounds__(256) void k_scan2(const int* __restrict__ bsum,
                                               int* __restrict__ boff) {
    __shared__ int s[256];
    int t = threadIdx.x;
    s[t] = (t < SCAN_BLOCKS) ? bsum[t] : 0;
    __syncthreads();
#pragma unroll
    for (int off = 1; off < 256; off <<= 1) {
        int v = (t >= off) ? s[t - off] : 0;
        __syncthreads();
        s[t] += v;
        __syncthreads();
    }
    if (t < SCAN_BLOCKS) boff[t] = (t > 0) ? s[t - 1] : 0;
}

__global__ __launch_bounds__(256) void k_scan3(const int* __restrict__ deg,
                                               const int* __restrict__ boff,
                                               int* __restrict__ row_ptr,
                                               int* __restrict__ cursor) {
    __shared__ int s[256];
    int t = threadIdx.x;
    int i = blockIdx.x * 256 + t;
    int d = (i < N_NODES) ? deg[i] : 0;
    s[t] = d;
    __syncthreads();
#pragma unroll
    for (int off = 1; off < 256; off <<= 1) {
        int v = (t >= off) ? s[t - off] : 0;
        __syncthreads();
        s[t] += v;
        __syncthreads();
    }
    if (i < N_NODES) {
        int excl = boff[blockIdx.x] + s[t] - d;
        row_ptr[i] = excl;
        cursor[i] = excl;
    }
    if (i == 0) row_ptr[N_NODES] = N_EDGES;
}

__global__ void k_fill(const int* __restrict__ src, const int* __restrict__ dst,
                       int* __restrict__ cursor, int* __restrict__ col) {
    int e = blockIdx.x * blockDim.x + threadIdx.x;
    if (e < N_EDGES) {
        int d = dst[e];
        int p = atomicAdd(&cursor[d], 1);
        col[p] = src[e];
    }
}

// ---------------- weight fp32 -> bf16 pack (w1: 128x64, w2: 128x128) ----------------

__global__ __launch_bounds__(256) void k_wpack(const float* __restrict__ w1,
                                               const float* __restrict__ w2,
                                               unsigned* __restrict__ w1b,
                                               unsigned* __restrict__ w2b) {
    int i = blockIdx.x * 256 + threadIdx.x;   // exact grid: 48 blocks = 12288 = 4096 + 8192
    if (i < 4096) {
        float2 v = ((const float2*)w1)[i];
        w1b[i] = bf16pack2(v.x, v.y);
    } else {
        int j = i - 4096;
        float2 v = ((const float2*)w2)[j];
        w2b[j] = bf16pack2(v.x, v.y);
    }
}

// ---------------- x pre-scale + bf16 pack: xs[m] = bf16(dinv[m] * x[m]) ----------------

__global__ __launch_bounds__(256) void k_xscale(const float* __restrict__ x,
                                                const float* __restrict__ dinv,
                                                unsigned* __restrict__ xs) {
    int i = blockIdx.x * 256 + threadIdx.x;   // exact grid: N_NODES*32
    int m = i >> 5;
    float dm = dinv[m];
    float2 v = ((const float2*)x)[i];
    xs[i] = bf16pack2(dm * v.x, dm * v.y);
}

// ---------------- gather64 (bf16 in, bf16 out): agg[d] = bf16(dinv[d]*(xs[d]+sum xs[s])) ----------------

__global__ __launch_bounds__(256) void k_gather64(const unsigned* __restrict__ xs,
                                                  const int* __restrict__ row_ptr,
                                                  const int* __restrict__ col,
                                                  const float* __restrict__ dinv,
                                                  unsigned* __restrict__ agg) {
    const int g = blockIdx.x * 8 + (threadIdx.x >> 5);   // grid 6250*8 = 50000 exact
    const int c = threadIdx.x & 31;

    unsigned v = xs[(size_t)g * 32 + c];
    float ax = bf16lo(v), ay = bf16hi(v);

    const int beg = row_ptr[g], end = row_ptr[g + 1];
    for (int j = beg; j < end; j += 8) {
        int   idx[8];
        float wt[8];
#pragma unroll
        for (int k = 0; k < 8; k++) {
            int jj = j + k;
            bool in = jj < end;
            idx[k] = in ? jj : (end - 1);
            wt[k] = in ? 1.f : 0.f;
        }
        int s[8];
#pragma unroll
        for (int k = 0; k < 8; k++) s[k] = col[idx[k]];
        unsigned u[8];
#pragma unroll
        for (int k = 0; k < 8; k++) u[k] = xs[(size_t)s[k] * 32 + c];
#pragma unroll
        for (int k = 0; k < 8; k++) {
            ax = fmaf(wt[k], bf16lo(u[k]), ax);
            ay = fmaf(wt[k], bf16hi(u[k]), ay);
        }
    }
    float dm = dinv[g];
    agg[(size_t)g * 32 + c] = bf16pack2(dm * ax, dm * ay);
}

// ---------------- gather128 (bf16 rows): out[d] = relu(dinv[d]*(ts[d]+sum ts[s]) + b) ----------------

__global__ __launch_bounds__(256) void k_gather128(const uint2* __restrict__ ts,
                                                   const int* __restrict__ row_ptr,
                                                   const int* __restrict__ col,
                                                   const float* __restrict__ dinv,
                                                   const float* __restrict__ bias,
                                                   float* __restrict__ out) {
    const int g = blockIdx.x * 8 + (threadIdx.x >> 5);   // grid 6250*8 = 50000 exact
    const int c = threadIdx.x & 31;

    uint2 v = ts[(size_t)g * 32 + c];
    float ax = bf16lo(v.x), ay = bf16hi(v.x), az = bf16lo(v.y), aw = bf16hi(v.y);

    const int beg = row_ptr[g], end = row_ptr[g + 1];
    for (int j = beg; j < end; j += 8) {
        int   idx[8];
        float wt[8];
#pragma unroll
        for (int k = 0; k < 8; k++) {
            int jj = j + k;
            bool in = jj < end;
            idx[k] = in ? jj : (end - 1);
            wt[k] = in ? 1.f : 0.f;
        }
        int s[8];
#pragma unroll
        for (int k = 0; k < 8; k++) s[k] = col[idx[k]];
        uint2 u[8];
#pragma unroll
        for (int k = 0; k < 8; k++) u[k] = ts[(size_t)s[k] * 32 + c];
#pragma unroll
        for (int k = 0; k < 8; k++) {
            ax = fmaf(wt[k], bf16lo(u[k].x), ax);
            ay = fmaf(wt[k], bf16hi(u[k].x), ay);
            az = fmaf(wt[k], bf16lo(u[k].y), az);
            aw = fmaf(wt[k], bf16hi(u[k].y), aw);
        }
    }
    float dm = dinv[g];
    float4 b = ((const float4*)bias)[c];
    float4 o;
    o.x = fmaxf(fmaf(dm, ax, b.x), 0.f);
    o.y = fmaxf(fmaf(dm, ay, b.y), 0.f);
    o.z = fmaxf(fmaf(dm, az, b.z), 0.f);
    o.w = fmaxf(fmaf(dm, aw, b.w), 0.f);
    ((float4*)out)[(size_t)g * 32 + c] = o;
}

// ---------------- MFMA bf16 GEMM: D[m][n] = sum_k X[m][k]*W[n][k]  (N=128) ----------------
// 64-row M-tile per 256-thread block (4 waves x 16 rows); full N=128; K in {64,128}.
// A,B fragments per verified gfx950 layouts: A[m=lane&15][k=quad*8+j],
// B[k=quad*8+j][n=lane&15], D row=quad*4+reg, col=lane&15.
// MODE 1: out = bf16(relu(acc + bias[n]));  MODE 2: out = bf16(dinv[m]*acc)

template<int K, int MODE>
__global__ __launch_bounds__(256) void k_gemm_mfma(const unsigned* __restrict__ Xb,
                                                   const unsigned* __restrict__ Wb,
                                                   const float* __restrict__ bias,
                                                   const float* __restrict__ dinv,
                                                   unsigned short* __restrict__ Ob) {
    constexpr int KU  = K / 2;        // uints per (unpadded) row
    constexpr int SP  = K + 8;        // padded shorts per LDS row (bank-stride 4 -> <=2-way)
    constexpr int SPU = SP / 2;       // padded uints per LDS row
    __shared__ __align__(16) unsigned As_u[64 * SPU];
    __shared__ __align__(16) unsigned Bs_u[128 * SPU];

    const int tid = threadIdx.x;
    const int bm = blockIdx.x * 64;

    for (int i = tid; i < 64 * KU; i += 256) {
        int r = i / KU, c = i % KU;    // KU is 32 or 64 (pow2)
        int m = bm + r;
        As_u[r * SPU + c] = (m < N_NODES) ? Xb[(size_t)m * KU + c] : 0u;
    }
    for (int i = tid; i < 128 * KU; i += 256) {
        int r = i / KU, c = i % KU;
        Bs_u[r * SPU + c] = Wb[r * KU + c];
    }
    __syncthreads();

    const int wv = tid >> 6;          // wave 0..3 -> rows bm+16*wv..+15
    const int lane = tid & 63;
    const int lr = lane & 15;
    const int q = lane >> 4;

    f32x4 acc[8];
#pragma unroll
    for (int nt = 0; nt < 8; nt++) acc[nt] = (f32x4){0.f, 0.f, 0.f, 0.f};

    const short* As_s = (const short*)As_u;
    const short* Bs_s = (const short*)Bs_u;
#pragma unroll
    for (int k0 = 0; k0 < K; k0 += 32) {
        bf16x8 a = *(const bf16x8*)(As_s + (wv * 16 + lr) * SP + k0 + q * 8);
#pragma unroll
        for (int nt = 0; nt < 8; nt++) {
            bf16x8 b = *(const bf16x8*)(Bs_s + (nt * 16 + lr) * SP + k0 + q * 8);
            acc[nt] = __builtin_amdgcn_mfma_f32_16x16x32_bf16(a, b, acc[nt], 0, 0, 0);
        }
    }

#pragma unroll
    for (int nt = 0; nt < 8; nt++) {
        int cN = nt * 16 + lr;
        float bv = (MODE == 1) ? bias[cN] : 0.f;
#pragma unroll
        for (int i = 0; i < 4; i++) {
            int m = bm + wv * 16 + q * 4 + i;
            if (m < N_NODES) {
                float v = acc[nt][i];
                if (MODE == 1) v = fmaxf(v + bv, 0.f);
                else           v = dinv[m] * v;
                Ob[(size_t)m * HID_DIM + cN] = bf16r(v);
            }
        }
    }
}

// ---------------- fused mean-pool + FC head ----------------

__global__ __launch_bounds__(256) void k_pool_fc(const float* __restrict__ h,
                                                 const int* __restrict__ gstart,
                                                 const float* __restrict__ fcw,
                                                 const float* __restrict__ fcb,
                                                 float* __restrict__ out) {
    const int g = blockIdx.x;
    const int f = threadIdx.x & 127;
    const int s = threadIdx.x >> 7;        // 0 or 1
    const int beg = gstart[g], end = gstart[g + 1];

    float acc = 0.f;
#pragma unroll 4
    for (int m = beg + s; m < end; m += 2)
        acc += h[(size_t)m * HID_DIM + f];

    __shared__ float tmp[256];
    __shared__ float pool[HID_DIM];
    tmp[threadIdx.x] = acc;
    __syncthreads();
    if (s == 0) {
        float tot = tmp[f] + tmp[128 + f];
        float c = fmaxf((float)(end - beg), 1.f);
        pool[f] = tot / c;
    }
    __syncthreads();
    if (threadIdx.x < OUT_DIM) {
        float a = fcb[threadIdx.x];
#pragma unroll 8
        for (int k = 0; k < HID_DIM; k++)
            a = fmaf(pool[k], fcw[threadIdx.x * HID_DIM + k], a);
        out[g * OUT_DIM + threadIdx.x] = a;
    }
}

// ---------------- launch ----------------

extern "C" void kernel_launch(void* const* d_in, const int* in_sizes, int n_in,
                              void* d_out, int out_size, void* d_ws, size_t ws_size,
                              hipStream_t stream) {
    const float* x   = (const float*)d_in[0];
    const int*  eidx = (const int*)d_in[1];
    const int* batch = (const int*)d_in[2];
    const float* w1  = (const float*)d_in[3];
    const float* b1  = (const float*)d_in[4];
    const float* w2  = (const float*)d_in[5];
    const float* b2  = (const float*)d_in[6];
    const float* fcw = (const float*)d_in[7];
    const float* fcb = (const float*)d_in[8];
    float* out = (float*)d_out;
    const int* src = eidx;             // edge_index[0]
    const int* dst = eidx + N_EDGES;   // edge_index[1]

    char* w = (char*)d_ws;
    // region A [0, 12.8M): layer1 xs(6.4M) + agg bf16(6.4M); after GEMM1 -> ts2 bf16(12.8M)
    unsigned* xs   = (unsigned*)(w);                  // 6,400,000 B
    unsigned* aggb = (unsigned*)(w + 6400000);        // 6,400,000 B
    uint2*    ts2  = (uint2*)(w);                     // 12,800,000 B (reuse of region A)
    unsigned short* h1b = (unsigned short*)(w + 12800000);  // 12,800,000 B
    float* bufB    = (float*)(w + 25600000);          // 25,600,000 B (out2 fp32)
    int*   deg     = (int*)  (w + 51200000);          // 200,000 B
    int*   row_ptr = (int*)  (w + 51400000);          // 200,064 B
    int*   cursor  = (int*)  (w + 51600064);          // 200,000 B
    float* dinv    = (float*)(w + 51800064);          // 200,000 B
    int*   col     = (int*)  (w + 52000064);          // 3,200,000 B
    int*   gstart  = (int*)  (w + 55200064);          // 260 B
    int*   bsum    = (int*)  (w + 55200384);          // 1024 B
    int*   boff    = (int*)  (w + 55201408);          // 1024 B
    unsigned* w1b  = (unsigned*)(w + 55202432);       // 16,384 B
    unsigned* w2b  = (unsigned*)(w + 55218816);       // 32,768 B  (end ~55.25 MB)

    dim3 b256(256);

    // CSR build (graph static across both layers) + graph boundaries + weight pack
    hipMemsetAsync(deg, 0, N_NODES * sizeof(int), stream);
    k_degcount<<<dim3((N_EDGES + 255) / 256), b256, 0, stream>>>(dst, deg);
    k_wpack<<<dim3(48), b256, 0, stream>>>(w1, w2, w1b, w2b);
    k_scan1<<<dim3(SCAN_BLOCKS), b256, 0, stream>>>(deg, bsum, dinv, batch, gstart);
    k_scan2<<<dim3(1), b256, 0, stream>>>(bsum, boff);
    k_scan3<<<dim3(SCAN_BLOCKS), b256, 0, stream>>>(deg, boff, row_ptr, cursor);
    k_fill<<<dim3((N_EDGES + 255) / 256), b256, 0, stream>>>(src, dst, cursor, col);

    // layer 1 (aggregate-then-transform, all-bf16 payloads):
    k_xscale<<<dim3(N_NODES * 32 / 256), b256, 0, stream>>>(x, dinv, xs);
    k_gather64<<<dim3(N_NODES / 8), b256, 0, stream>>>(xs, row_ptr, col, dinv, aggb);
    k_gemm_mfma<IN_DIM, 1><<<dim3((N_NODES + 63) / 64), b256, 0, stream>>>(aggb, w1b, b1, dinv, h1b);

    // layer 2 (transform-then-aggregate):
    k_gemm_mfma<HID_DIM, 2><<<dim3((N_NODES + 63) / 64), b256, 0, stream>>>((const unsigned*)h1b, w2b, b1, dinv, (unsigned short*)ts2);
    k_gather128<<<dim3(N_NODES / 8), b256, 0, stream>>>(ts2, row_ptr, col, dinv, b2, bufB);

    // fused mean-pool + FC head
    k_pool_fc<<<dim3(N_GRAPHS), b256, 0, stream>>>(bufB, gstart, fcw, fcb, out);
}